// Round 4
// baseline (16447.040 us; speedup 1.0000x reference)
//
#include <hip/hip_runtime.h>
#include <cstdint>
#include <cstddef>

// B=2, S=2048, D=768, H=12, DH=64, T=64, R=50, FF=3072
// I/O dtype: fp32 (per reference). Internal compute: bf16 MFMA + fp32 accum.
// R3 diagnostic proved inputs are fp32 (bf16-reinterpreted X contains NaN).

typedef __bf16 bf16;
typedef __bf16 bf16x8 __attribute__((ext_vector_type(8)));
typedef __bf16 bf16x4 __attribute__((ext_vector_type(4)));
typedef float  floatx4 __attribute__((ext_vector_type(4)));

// ---------------------------------------------------------------------------
// fp32 -> bf16 bulk convert. n % 4 == 0; grid covers n/4 threads.
// ---------------------------------------------------------------------------
__global__ __launch_bounds__(256) void k_cvt(const float* __restrict__ x,
                                             bf16* __restrict__ y, long long n) {
  long long i = ((long long)blockIdx.x * 256 + threadIdx.x) * 4;
  if (i < n) {
    float4 v = *(const float4*)(x + i);
    bf16x4 o;
    o[0] = (bf16)v.x; o[1] = (bf16)v.y; o[2] = (bf16)v.z; o[3] = (bf16)v.w;
    *(bf16x4*)(y + i) = o;
  }
}

// ---------------------------------------------------------------------------
// Weight transpose + cvt: Wt[n][k] = (bf16)W[k][n].  64x64 tiles, pad-72 LDS.
// grid: (N/64, K/64), block 256.
// ---------------------------------------------------------------------------
__global__ __launch_bounds__(256) void k_transpose(const float* __restrict__ W,
                                                   bf16* __restrict__ Wt,
                                                   int K, int N) {
  __shared__ bf16 tile[64][72];
  int n0 = blockIdx.x * 64, k0 = blockIdx.y * 64;
  int t = threadIdx.x;
  int r = t >> 2, cg = (t & 3) * 16;
  const float* src = W + (size_t)(k0 + r) * N + n0 + cg;
  float tmp[16];
  *(float4*)&tmp[0]  = *(const float4*)(src);
  *(float4*)&tmp[4]  = *(const float4*)(src + 4);
  *(float4*)&tmp[8]  = *(const float4*)(src + 8);
  *(float4*)&tmp[12] = *(const float4*)(src + 12);
#pragma unroll
  for (int i = 0; i < 16; ++i) tile[r][cg + i] = (bf16)tmp[i];
  __syncthreads();
  bf16* dst = Wt + (size_t)(n0 + r) * K + k0 + cg;
#pragma unroll
  for (int g = 0; g < 2; ++g) {
    bf16x8 pack;
#pragma unroll
    for (int i = 0; i < 8; ++i) pack[i] = tile[cg + g * 8 + i][r];
    *(bf16x8*)(dst + g * 8) = pack;
  }
}

// ---------------------------------------------------------------------------
// Pad tag_emb (64x768 fp32) into 128x768 bf16 (rows 64..127 zero).
// ---------------------------------------------------------------------------
__global__ void k_pad_tags(const float* __restrict__ tag, bf16* __restrict__ out) {
  int i = blockIdx.x * 256 + threadIdx.x;
  if (i < 64 * 768) out[i] = (bf16)tag[i];
  else if (i < 128 * 768) out[i] = (bf16)0.f;
}

// ---------------------------------------------------------------------------
// GEMM: C[M,N] = A[M,K] @ B[K,N] + bias(fp32), B transposed as Bt[N,K], bf16.
// 128x128 tile, BK=32, 256 threads = 4 waves 2x2, 4x4 16x16x32 accs/wave.
// act: 0 = none, 1 = exact-erf GELU. grid (M/128, N/128); no bounds guards.
// ---------------------------------------------------------------------------
__global__ __launch_bounds__(256) void k_gemm(const bf16* __restrict__ A,
                                              const bf16* __restrict__ Bt,
                                              const float* __restrict__ bias,
                                              bf16* __restrict__ C,
                                              int M, int N, int K, int act) {
  __shared__ bf16 As[128 * 32];
  __shared__ bf16 Bs[128 * 32];
  int tid = threadIdx.x;
  int lane = tid & 63, wave = tid >> 6;
  int wm = wave & 1, wn = wave >> 1;
  int m0 = blockIdx.x * 128, n0 = blockIdx.y * 128;

  const bf16* Ap = A + (size_t)(m0 + (tid >> 2)) * K + (tid & 3) * 8;
  const bf16* Bp = Bt + (size_t)(n0 + (tid >> 2)) * K + (tid & 3) * 8;
  int ldst = (tid >> 2) * 32 + (tid & 3) * 8;

  floatx4 zero = {0.f, 0.f, 0.f, 0.f};
  floatx4 acc[4][4];
#pragma unroll
  for (int i = 0; i < 4; ++i)
#pragma unroll
    for (int j = 0; j < 4; ++j) acc[i][j] = zero;

  bf16x8 va0 = *(const bf16x8*)(Ap);
  bf16x8 va1 = *(const bf16x8*)(Ap + (size_t)64 * K);
  bf16x8 vb0 = *(const bf16x8*)(Bp);
  bf16x8 vb1 = *(const bf16x8*)(Bp + (size_t)64 * K);

  for (int k = 0; k < K; k += 32) {
    __syncthreads();
    *(bf16x8*)&As[ldst] = va0;
    *(bf16x8*)&As[ldst + 64 * 32] = va1;
    *(bf16x8*)&Bs[ldst] = vb0;
    *(bf16x8*)&Bs[ldst + 64 * 32] = vb1;
    __syncthreads();
    if (k + 32 < K) {
      va0 = *(const bf16x8*)(Ap + k + 32);
      va1 = *(const bf16x8*)(Ap + (size_t)64 * K + k + 32);
      vb0 = *(const bf16x8*)(Bp + k + 32);
      vb1 = *(const bf16x8*)(Bp + (size_t)64 * K + k + 32);
    }
    bf16x8 a_frag[4], b_frag[4];
#pragma unroll
    for (int mt = 0; mt < 4; ++mt)
      a_frag[mt] = *(const bf16x8*)&As[(wm * 64 + mt * 16 + (lane & 15)) * 32 + (lane >> 4) * 8];
#pragma unroll
    for (int nt = 0; nt < 4; ++nt)
      b_frag[nt] = *(const bf16x8*)&Bs[(wn * 64 + nt * 16 + (lane & 15)) * 32 + (lane >> 4) * 8];
#pragma unroll
    for (int mt = 0; mt < 4; ++mt)
#pragma unroll
      for (int nt = 0; nt < 4; ++nt)
        acc[mt][nt] = __builtin_amdgcn_mfma_f32_16x16x32_bf16(a_frag[mt], b_frag[nt], acc[mt][nt], 0, 0, 0);
  }

  // epilogue: C layout col=lane&15, row=(lane>>4)*4+r  (m89/m91-verified)
#pragma unroll
  for (int nt = 0; nt < 4; ++nt) {
    int col = n0 + wn * 64 + nt * 16 + (lane & 15);
    float bv = bias[col];
#pragma unroll
    for (int mt = 0; mt < 4; ++mt) {
#pragma unroll
      for (int r = 0; r < 4; ++r) {
        int row = m0 + wm * 64 + mt * 16 + (lane >> 4) * 4 + r;
        float v = acc[mt][nt][r] + bv;
        if (act) v = 0.5f * v * (1.f + erff(v * 0.70710678118654752f));
        C[(size_t)row * N + col] = (bf16)v;
      }
    }
  }
}

// ---------------------------------------------------------------------------
// Flash-style attention (scalar VALU, online softmax). Q/K/V/O bf16, layout
// [b*S + s][h*64 + d]. Band mask is ADDITIVE (+1 inside |i-j|<=R); softmax
// over ALL Skv keys. grid (S/64, B*H); wave handles 16 query rows.
// ---------------------------------------------------------------------------
__global__ __launch_bounds__(256) void k_flash_attn(const bf16* __restrict__ Q,
                                                    const bf16* __restrict__ K,
                                                    const bf16* __restrict__ V,
                                                    bf16* __restrict__ O,
                                                    int S, int Skv,
                                                    long long kv_bstride, int bandR) {
  const int NH = 12, DHc = 64;
  const size_t D = 768;
  int qt = blockIdx.x, bh = blockIdx.y;
  int bb = bh / NH, h = bh % NH;
  const bf16* Qb = Q + ((size_t)bb * S) * D + h * DHc;
  const bf16* Kb = K + (size_t)bb * kv_bstride + h * DHc;
  const bf16* Vb = V + (size_t)bb * kv_bstride + h * DHc;
  bf16* Ob = O + ((size_t)bb * S) * D + h * DHc;

  __shared__ bf16 Qs[64][72];
  __shared__ bf16 Ks[64][72];
  __shared__ bf16 Vt[64][72];
  __shared__ float Ps[4][64];

  int tid = threadIdx.x, wave = tid >> 6, lane = tid & 63;
  int r = tid >> 2, cg = (tid & 3) * 16;

  {
    const bf16* src = Qb + (size_t)(qt * 64 + r) * D + cg;
    *(bf16x8*)&Qs[r][cg] = *(const bf16x8*)src;
    *(bf16x8*)&Qs[r][cg + 8] = *(const bf16x8*)(src + 8);
  }

  float m_i[16], l_i[16], acc[16];
#pragma unroll
  for (int i = 0; i < 16; ++i) { m_i[i] = -1e30f; l_i[i] = 0.f; acc[i] = 0.f; }

  for (int kc = 0; kc < Skv; kc += 64) {
    __syncthreads();
    {
      const bf16* src = Kb + (size_t)(kc + r) * D + cg;
      *(bf16x8*)&Ks[r][cg] = *(const bf16x8*)src;
      *(bf16x8*)&Ks[r][cg + 8] = *(const bf16x8*)(src + 8);
      const bf16* vs = Vb + (size_t)(kc + r) * D + cg;
      bf16x8 w0 = *(const bf16x8*)vs;
      bf16x8 w1 = *(const bf16x8*)(vs + 8);
#pragma unroll
      for (int i = 0; i < 8; ++i) Vt[cg + i][r] = w0[i];
#pragma unroll
      for (int i = 0; i < 8; ++i) Vt[cg + 8 + i][r] = w1[i];
    }
    __syncthreads();

#pragma unroll
    for (int rr = 0; rr < 16; ++rr) {
      int qrow = wave * 16 + rr;
      int qi = qt * 64 + qrow;
      float s = 0.f;
#pragma unroll
      for (int d8 = 0; d8 < 64; d8 += 8) {
        bf16x8 k8 = *(const bf16x8*)&Ks[lane][d8];
        bf16x8 q8 = *(const bf16x8*)&Qs[qrow][d8];
#pragma unroll
        for (int i = 0; i < 8; ++i) s += (float)q8[i] * (float)k8[i];
      }
      s *= 0.125f;
      if (bandR >= 0) {
        int diff = qi - (kc + lane);
        if (diff < 0) diff = -diff;
        if (diff <= bandR) s += 1.0f;
      }
      float cm = s;
#pragma unroll
      for (int off = 32; off > 0; off >>= 1) cm = fmaxf(cm, __shfl_xor(cm, off));
      float mnew = fmaxf(m_i[rr], cm);
      float p = exp2f((s - mnew) * 1.44269504f);
      float alpha = exp2f((m_i[rr] - mnew) * 1.44269504f);
      m_i[rr] = mnew;
      float ps = p;
#pragma unroll
      for (int off = 32; off > 0; off >>= 1) ps += __shfl_xor(ps, off);
      l_i[rr] = l_i[rr] * alpha + ps;
      Ps[wave][lane] = p;
      float a = acc[rr] * alpha;
#pragma unroll
      for (int j8 = 0; j8 < 64; j8 += 8) {
        float4 p0 = *(const float4*)&Ps[wave][j8];
        float4 p1 = *(const float4*)&Ps[wave][j8 + 4];
        bf16x8 v8 = *(const bf16x8*)&Vt[lane][j8];
        a += p0.x * (float)v8[0] + p0.y * (float)v8[1] + p0.z * (float)v8[2] + p0.w * (float)v8[3]
           + p1.x * (float)v8[4] + p1.y * (float)v8[5] + p1.z * (float)v8[6] + p1.w * (float)v8[7];
      }
      acc[rr] = a;
    }
  }
#pragma unroll
  for (int rr = 0; rr < 16; ++rr) {
    int qrow = wave * 16 + rr;
    float o = acc[rr] / fmaxf(l_i[rr], 1e-20f);
    Ob[(size_t)(qt * 64 + qrow) * D + lane] = (bf16)o;
  }
}

// ---------------------------------------------------------------------------
// out = LayerNorm(Y + X) * g + b.  Y bf16; X dtype TR; out dtype TO.
// One wave per 768-wide row; 4 rows/block. In-place safe.
// ---------------------------------------------------------------------------
template <typename TR, typename TO>
__global__ __launch_bounds__(256) void k_add_ln(const bf16* __restrict__ Y,
                                                const TR* __restrict__ X,
                                                const float* __restrict__ g,
                                                const float* __restrict__ b,
                                                TO* __restrict__ out) {
  int wave = threadIdx.x >> 6, lane = threadIdx.x & 63;
  int row = blockIdx.x * 4 + wave;
  const bf16* y = Y + (size_t)row * 768;
  const TR* x = X + (size_t)row * 768;
  float v[12];
  float s = 0.f, s2 = 0.f;
#pragma unroll
  for (int c = 0; c < 3; ++c) {
    int idx = c * 256 + lane * 4;
    bf16x4 yv = *(const bf16x4*)(y + idx);
    float xv[4];
    if constexpr (__is_same(TR, float)) {
      float4 t = *(const float4*)(x + idx);
      xv[0] = t.x; xv[1] = t.y; xv[2] = t.z; xv[3] = t.w;
    } else {
      bf16x4 t = *(const bf16x4*)(x + idx);
#pragma unroll
      for (int i = 0; i < 4; ++i) xv[i] = (float)t[i];
    }
#pragma unroll
    for (int i = 0; i < 4; ++i) {
      float t = (float)yv[i] + xv[i];
      v[c * 4 + i] = t; s += t; s2 += t * t;
    }
  }
#pragma unroll
  for (int off = 32; off > 0; off >>= 1) { s += __shfl_xor(s, off); s2 += __shfl_xor(s2, off); }
  float mean = s * (1.f / 768.f);
  float var = s2 * (1.f / 768.f) - mean * mean;
  var = fmaxf(var, 0.f);
  float inv = rsqrtf(var + 1e-12f);
  TO* o = out + (size_t)row * 768;
#pragma unroll
  for (int c = 0; c < 3; ++c) {
    int idx = c * 256 + lane * 4;
    float4 gv = *(const float4*)(g + idx);
    float4 bv = *(const float4*)(b + idx);
    float r0 = (v[c * 4 + 0] - mean) * inv * gv.x + bv.x;
    float r1 = (v[c * 4 + 1] - mean) * inv * gv.y + bv.y;
    float r2 = (v[c * 4 + 2] - mean) * inv * gv.z + bv.z;
    float r3 = (v[c * 4 + 3] - mean) * inv * gv.w + bv.w;
    if constexpr (__is_same(TO, float)) {
      float4 ov = {r0, r1, r2, r3};
      *(float4*)(o + idx) = ov;
    } else {
      bf16x4 ov;
      ov[0] = (bf16)r0; ov[1] = (bf16)r1; ov[2] = (bf16)r2; ov[3] = (bf16)r3;
      *(bf16x4*)(o + idx) = ov;
    }
  }
}

// ---------------------------------------------------------------------------
extern "C" void kernel_launch(void* const* d_in, const int* in_sizes, int n_in,
                              void* d_out, int out_size, void* d_ws, size_t ws_size,
                              hipStream_t stream) {
  (void)in_sizes; (void)n_in; (void)out_size; (void)ws_size;
  const float* X     = (const float*)d_in[0];
  const float* tag   = (const float*)d_in[1];
  const float* sa_wq = (const float*)d_in[2];
  const float* sa_bq = (const float*)d_in[3];
  const float* sa_wk = (const float*)d_in[4];
  const float* sa_bk = (const float*)d_in[5];
  const float* sa_wv = (const float*)d_in[6];
  const float* sa_bv = (const float*)d_in[7];
  const float* sa_wo = (const float*)d_in[8];
  const float* sa_bo = (const float*)d_in[9];
  const float* sa_lg = (const float*)d_in[10];
  const float* sa_lb = (const float*)d_in[11];
  const float* ca_wq = (const float*)d_in[12];
  const float* ca_bq = (const float*)d_in[13];
  const float* ca_wk = (const float*)d_in[14];
  const float* ca_bk = (const float*)d_in[15];
  const float* ca_wv = (const float*)d_in[16];
  const float* ca_bv = (const float*)d_in[17];
  const float* ca_wo = (const float*)d_in[18];
  const float* ca_bo = (const float*)d_in[19];
  const float* ca_lg = (const float*)d_in[20];
  const float* ca_lb = (const float*)d_in[21];
  const float* ff_w1 = (const float*)d_in[22];
  const float* ff_b1 = (const float*)d_in[23];
  const float* ff_w2 = (const float*)d_in[24];
  const float* ff_b2 = (const float*)d_in[25];
  const float* ff_lg = (const float*)d_in[26];
  const float* ff_lb = (const float*)d_in[27];

  float* out = (float*)d_out;
  bf16* outb = (bf16*)d_out;  // fp32 out buffer doubles as bf16 ctx scratch
  const long long NTOK = (long long)4096 * 768;

  // ---- workspace: ~34.8 MB (all internal buffers bf16) ----
  const size_t SLOT = (size_t)4096 * 768;
  bf16* Xb     = (bf16*)d_ws;                  // bf16 copy of hidden_states
  bf16* slotA  = Xb + SLOT;                    // Q -> y1 -> attn1 -> attn2
  bf16* slotB  = slotA + SLOT;                 // K -> Q2 -> y2 ; then ff1t
  bf16* slotC  = slotB + SLOT;                 // V ; then ff2t
  bf16* interC = slotC + SLOT;                 // FFN inter chunk 1024x3072
  bf16* y3c    = interC + (size_t)1024 * 3072; // FFN2 out chunk 1024x768
  bf16* Wt     = y3c + (size_t)1024 * 768;     // 768x768 transpose scratch
  bf16* tagp   = Wt + (size_t)768 * 768;
  bf16* k2     = tagp + (size_t)128 * 768;
  bf16* v2     = k2 + (size_t)128 * 768;

  dim3 blk(256);
  const long long kvb_sa = (long long)2048 * 768;

  k_cvt<<<dim3(3072), blk, 0, stream>>>(X, Xb, NTOK);
  k_pad_tags<<<dim3(384), blk, 0, stream>>>(tag, tagp);

  // ---- self-attention ----
  k_transpose<<<dim3(12, 12), blk, 0, stream>>>(sa_wq, Wt, 768, 768);
  k_gemm<<<dim3(32, 6), blk, 0, stream>>>(Xb, Wt, sa_bq, slotA, 4096, 768, 768, 0);  // Q
  k_transpose<<<dim3(12, 12), blk, 0, stream>>>(sa_wk, Wt, 768, 768);
  k_gemm<<<dim3(32, 6), blk, 0, stream>>>(Xb, Wt, sa_bk, slotB, 4096, 768, 768, 0);  // K
  k_transpose<<<dim3(12, 12), blk, 0, stream>>>(sa_wv, Wt, 768, 768);
  k_gemm<<<dim3(32, 6), blk, 0, stream>>>(Xb, Wt, sa_bv, slotC, 4096, 768, 768, 0);  // V
  k_flash_attn<<<dim3(32, 24), blk, 0, stream>>>(slotA, slotB, slotC, outb, 2048, 2048, kvb_sa, 50);
  k_transpose<<<dim3(12, 12), blk, 0, stream>>>(sa_wo, Wt, 768, 768);
  k_gemm<<<dim3(32, 6), blk, 0, stream>>>(outb, Wt, sa_bo, slotA, 4096, 768, 768, 0);   // y1
  k_add_ln<float, bf16><<<dim3(1024), blk, 0, stream>>>(slotA, X, sa_lg, sa_lb, slotA); // attn1 (fp32 residual)

  // ---- cross-attention (64 tag keys, batch-shared) ----
  k_transpose<<<dim3(12, 12), blk, 0, stream>>>(ca_wq, Wt, 768, 768);
  k_gemm<<<dim3(32, 6), blk, 0, stream>>>(slotA, Wt, ca_bq, slotB, 4096, 768, 768, 0);  // Q2
  k_transpose<<<dim3(12, 12), blk, 0, stream>>>(ca_wk, Wt, 768, 768);
  k_gemm<<<dim3(1, 6), blk, 0, stream>>>(tagp, Wt, ca_bk, k2, 128, 768, 768, 0);        // K2
  k_transpose<<<dim3(12, 12), blk, 0, stream>>>(ca_wv, Wt, 768, 768);
  k_gemm<<<dim3(1, 6), blk, 0, stream>>>(tagp, Wt, ca_bv, v2, 128, 768, 768, 0);        // V2
  k_flash_attn<<<dim3(32, 24), blk, 0, stream>>>(slotB, k2, v2, outb, 2048, 64, 0, -1); // ctx2
  k_transpose<<<dim3(12, 12), blk, 0, stream>>>(ca_wo, Wt, 768, 768);
  k_gemm<<<dim3(32, 6), blk, 0, stream>>>(outb, Wt, ca_bo, slotB, 4096, 768, 768, 0);   // y2
  k_add_ln<bf16, bf16><<<dim3(1024), blk, 0, stream>>>(slotB, slotA, ca_lg, ca_lb, slotA); // attn2 -> A

  // ---- FFN, M-chunked (4 x 1024 rows), fused final add+LN per chunk ----
  k_transpose<<<dim3(48, 12), blk, 0, stream>>>(ff_w1, slotB, 768, 3072);  // ff1t [3072][768]
  k_transpose<<<dim3(12, 48), blk, 0, stream>>>(ff_w2, slotC, 3072, 768);  // ff2t [768][3072]
  for (int mc = 0; mc < 4; ++mc) {
    const bf16* a2 = slotA + (size_t)mc * 1024 * 768;
    k_gemm<<<dim3(8, 24), blk, 0, stream>>>(a2, slotB, ff_b1, interC, 1024, 3072, 768, 1);
    k_gemm<<<dim3(8, 6), blk, 0, stream>>>(interC, slotC, ff_b2, y3c, 1024, 768, 3072, 0);
    k_add_ln<bf16, float><<<dim3(256), blk, 0, stream>>>(y3c, a2, ff_lg, ff_lb,
                                                         out + (size_t)mc * 1024 * 768);
  }
}

// Round 5
// 759.540 us; speedup vs baseline: 21.6539x; 21.6539x over previous
//
#include <hip/hip_runtime.h>
#include <cstdint>
#include <cstddef>

// B=2, S=2048, D=768, H=12, DH=64, T=64, R=50, FF=3072
// I/O dtype: fp32 (per reference). Internal compute: bf16 MFMA + fp32 accum.
// R4: scalar flash attn was latency-bound (VALUBusy 6.5%, VGPR 256, occ 10%).
// R5: MFMA attention (QK^T and PV on matrix cores, online softmax in C-layout).

typedef __bf16 bf16;
typedef __bf16 bf16x8 __attribute__((ext_vector_type(8)));
typedef __bf16 bf16x4 __attribute__((ext_vector_type(4)));
typedef float  floatx4 __attribute__((ext_vector_type(4)));

// ---------------------------------------------------------------------------
// fp32 -> bf16 bulk convert. n % 4 == 0.
// ---------------------------------------------------------------------------
__global__ __launch_bounds__(256) void k_cvt(const float* __restrict__ x,
                                             bf16* __restrict__ y, long long n) {
  long long i = ((long long)blockIdx.x * 256 + threadIdx.x) * 4;
  if (i < n) {
    float4 v = *(const float4*)(x + i);
    bf16x4 o;
    o[0] = (bf16)v.x; o[1] = (bf16)v.y; o[2] = (bf16)v.z; o[3] = (bf16)v.w;
    *(bf16x4*)(y + i) = o;
  }
}

// ---------------------------------------------------------------------------
// Weight transpose + cvt: Wt[n][k] = (bf16)W[k][n].  64x64 tiles, pad-72 LDS.
// ---------------------------------------------------------------------------
__global__ __launch_bounds__(256) void k_transpose(const float* __restrict__ W,
                                                   bf16* __restrict__ Wt,
                                                   int K, int N) {
  __shared__ bf16 tile[64][72];
  int n0 = blockIdx.x * 64, k0 = blockIdx.y * 64;
  int t = threadIdx.x;
  int r = t >> 2, cg = (t & 3) * 16;
  const float* src = W + (size_t)(k0 + r) * N + n0 + cg;
  float tmp[16];
  *(float4*)&tmp[0]  = *(const float4*)(src);
  *(float4*)&tmp[4]  = *(const float4*)(src + 4);
  *(float4*)&tmp[8]  = *(const float4*)(src + 8);
  *(float4*)&tmp[12] = *(const float4*)(src + 12);
#pragma unroll
  for (int i = 0; i < 16; ++i) tile[r][cg + i] = (bf16)tmp[i];
  __syncthreads();
  bf16* dst = Wt + (size_t)(n0 + r) * K + k0 + cg;
#pragma unroll
  for (int g = 0; g < 2; ++g) {
    bf16x8 pack;
#pragma unroll
    for (int i = 0; i < 8; ++i) pack[i] = tile[cg + g * 8 + i][r];
    *(bf16x8*)(dst + g * 8) = pack;
  }
}

// ---------------------------------------------------------------------------
__global__ void k_pad_tags(const float* __restrict__ tag, bf16* __restrict__ out) {
  int i = blockIdx.x * 256 + threadIdx.x;
  if (i < 64 * 768) out[i] = (bf16)tag[i];
  else if (i < 128 * 768) out[i] = (bf16)0.f;
}

// ---------------------------------------------------------------------------
// GEMM: C[M,N] = A[M,K] @ B[K,N] + bias(fp32), B transposed as Bt[N,K], bf16.
// 128x128 tile, BK=32, 4 waves 2x2, 4x4 16x16x32 accs/wave.
// ---------------------------------------------------------------------------
__global__ __launch_bounds__(256) void k_gemm(const bf16* __restrict__ A,
                                              const bf16* __restrict__ Bt,
                                              const float* __restrict__ bias,
                                              bf16* __restrict__ C,
                                              int M, int N, int K, int act) {
  __shared__ bf16 As[128 * 32];
  __shared__ bf16 Bs[128 * 32];
  int tid = threadIdx.x;
  int lane = tid & 63, wave = tid >> 6;
  int wm = wave & 1, wn = wave >> 1;
  int m0 = blockIdx.x * 128, n0 = blockIdx.y * 128;

  const bf16* Ap = A + (size_t)(m0 + (tid >> 2)) * K + (tid & 3) * 8;
  const bf16* Bp = Bt + (size_t)(n0 + (tid >> 2)) * K + (tid & 3) * 8;
  int ldst = (tid >> 2) * 32 + (tid & 3) * 8;

  floatx4 zero = {0.f, 0.f, 0.f, 0.f};
  floatx4 acc[4][4];
#pragma unroll
  for (int i = 0; i < 4; ++i)
#pragma unroll
    for (int j = 0; j < 4; ++j) acc[i][j] = zero;

  bf16x8 va0 = *(const bf16x8*)(Ap);
  bf16x8 va1 = *(const bf16x8*)(Ap + (size_t)64 * K);
  bf16x8 vb0 = *(const bf16x8*)(Bp);
  bf16x8 vb1 = *(const bf16x8*)(Bp + (size_t)64 * K);

  for (int k = 0; k < K; k += 32) {
    __syncthreads();
    *(bf16x8*)&As[ldst] = va0;
    *(bf16x8*)&As[ldst + 64 * 32] = va1;
    *(bf16x8*)&Bs[ldst] = vb0;
    *(bf16x8*)&Bs[ldst + 64 * 32] = vb1;
    __syncthreads();
    if (k + 32 < K) {
      va0 = *(const bf16x8*)(Ap + k + 32);
      va1 = *(const bf16x8*)(Ap + (size_t)64 * K + k + 32);
      vb0 = *(const bf16x8*)(Bp + k + 32);
      vb1 = *(const bf16x8*)(Bp + (size_t)64 * K + k + 32);
    }
    bf16x8 a_frag[4], b_frag[4];
#pragma unroll
    for (int mt = 0; mt < 4; ++mt)
      a_frag[mt] = *(const bf16x8*)&As[(wm * 64 + mt * 16 + (lane & 15)) * 32 + (lane >> 4) * 8];
#pragma unroll
    for (int nt = 0; nt < 4; ++nt)
      b_frag[nt] = *(const bf16x8*)&Bs[(wn * 64 + nt * 16 + (lane & 15)) * 32 + (lane >> 4) * 8];
#pragma unroll
    for (int mt = 0; mt < 4; ++mt)
#pragma unroll
      for (int nt = 0; nt < 4; ++nt)
        acc[mt][nt] = __builtin_amdgcn_mfma_f32_16x16x32_bf16(a_frag[mt], b_frag[nt], acc[mt][nt], 0, 0, 0);
  }

#pragma unroll
  for (int nt = 0; nt < 4; ++nt) {
    int col = n0 + wn * 64 + nt * 16 + (lane & 15);
    float bv = bias[col];
#pragma unroll
    for (int mt = 0; mt < 4; ++mt) {
#pragma unroll
      for (int r = 0; r < 4; ++r) {
        int row = m0 + wm * 64 + mt * 16 + (lane >> 4) * 4 + r;
        float v = acc[mt][nt][r] + bv;
        if (act) v = 0.5f * v * (1.f + erff(v * 0.70710678118654752f));
        C[(size_t)row * N + col] = (bf16)v;
      }
    }
  }
}

// ---------------------------------------------------------------------------
// MFMA flash attention. Q/K/V/O bf16, layout [b*S+s][h*64+d].
// Band mask ADDITIVE (+1 inside |i-j|<=R); softmax over ALL Skv keys.
// grid (S/64, B*H), block 256 = 4 waves; wave w owns Q rows [w*16, w*16+16).
// Per 64-key chunk: QK^T = 8 MFMAs (4 key-tiles x K=64), online softmax on
// C-layout (row=quad*4+rr, col=l16; quad-local shfl_xor reductions),
// P->LDS->A-layout round trip, PV = 8 MFMAs vs transposed-V tile.
// ---------------------------------------------------------------------------
__global__ __launch_bounds__(256) void k_attn_mfma(const bf16* __restrict__ Q,
                                                   const bf16* __restrict__ K,
                                                   const bf16* __restrict__ V,
                                                   bf16* __restrict__ O,
                                                   int S, int Skv,
                                                   long long kv_bstride, int bandR) {
  const int NH = 12;
  const size_t D = 768;
  int qt = blockIdx.x, bh = blockIdx.y;
  int bb = bh / NH, h = bh % NH;
  const bf16* Qb = Q + ((size_t)bb * S) * D + h * 64;
  const bf16* Kb = K + (size_t)bb * kv_bstride + h * 64;
  const bf16* Vb = V + (size_t)bb * kv_bstride + h * 64;
  bf16* Ob = O + ((size_t)bb * S) * D + h * 64;

  __shared__ bf16 Qs[64][72];      // [q_row][d]
  __shared__ bf16 Ks[64][72];      // [key][d]
  __shared__ bf16 Vt[64][72];      // [d][key]
  __shared__ bf16 Ps[4][16][72];   // [wave][q][key] (pad 72)

  int tid = threadIdx.x, wave = tid >> 6, lane = tid & 63;
  int quad = lane >> 4, l16 = lane & 15;
  int r = tid >> 2, cg = (tid & 3) * 16;

  {  // stage Q tile once
    const bf16* src = Qb + (size_t)(qt * 64 + r) * D + cg;
    *(bf16x8*)&Qs[r][cg] = *(const bf16x8*)src;
    *(bf16x8*)&Qs[r][cg + 8] = *(const bf16x8*)(src + 8);
  }

  float m_i[4], l_i[4];
  floatx4 acc[4];  // acc[nt][rr]: dh tile nt, q row = quad*4+rr
#pragma unroll
  for (int i = 0; i < 4; ++i) {
    m_i[i] = -1e30f; l_i[i] = 0.f;
    acc[i] = floatx4{0.f, 0.f, 0.f, 0.f};
  }

  for (int kc = 0; kc < Skv; kc += 64) {
    __syncthreads();  // prior chunk's reads done (also orders Q staging)
    {
      const bf16* src = Kb + (size_t)(kc + r) * D + cg;
      *(bf16x8*)&Ks[r][cg] = *(const bf16x8*)src;
      *(bf16x8*)&Ks[r][cg + 8] = *(const bf16x8*)(src + 8);
      const bf16* vs = Vb + (size_t)(kc + r) * D + cg;
      bf16x8 w0 = *(const bf16x8*)vs;
      bf16x8 w1 = *(const bf16x8*)(vs + 8);
#pragma unroll
      for (int i = 0; i < 8; ++i) Vt[cg + i][r] = w0[i];
#pragma unroll
      for (int i = 0; i < 8; ++i) Vt[cg + 8 + i][r] = w1[i];
    }
    __syncthreads();  // chunk staged

    // ---- QK^T: A[m=q=l16][k=d=quad*8+j], B[n=key=l16][k=d] ----
    bf16x8 aq0 = *(const bf16x8*)&Qs[wave * 16 + l16][quad * 8];
    bf16x8 aq1 = *(const bf16x8*)&Qs[wave * 16 + l16][32 + quad * 8];
    floatx4 s[4];
#pragma unroll
    for (int kt = 0; kt < 4; ++kt) {
      bf16x8 bk0 = *(const bf16x8*)&Ks[kt * 16 + l16][quad * 8];
      bf16x8 bk1 = *(const bf16x8*)&Ks[kt * 16 + l16][32 + quad * 8];
      floatx4 c = {0.f, 0.f, 0.f, 0.f};
      c = __builtin_amdgcn_mfma_f32_16x16x32_bf16(aq0, bk0, c, 0, 0, 0);
      c = __builtin_amdgcn_mfma_f32_16x16x32_bf16(aq1, bk1, c, 0, 0, 0);
      s[kt] = c;
    }

    // ---- scale + band mask (C layout: row=quad*4+rr, col=kt*16+l16) ----
#pragma unroll
    for (int kt = 0; kt < 4; ++kt) {
      int kj = kc + kt * 16 + l16;
#pragma unroll
      for (int rr = 0; rr < 4; ++rr) {
        float v = s[kt][rr] * 0.125f;  // 1/sqrt(64)
        if (bandR >= 0) {
          int qi = qt * 64 + wave * 16 + quad * 4 + rr;
          int d = qi - kj; if (d < 0) d = -d;
          if (d <= bandR) v += 1.0f;
        }
        s[kt][rr] = v;
      }
    }

    // ---- online softmax per q row (reduce across quad's 16 lanes) ----
#pragma unroll
    for (int rr = 0; rr < 4; ++rr) {
      float cm = fmaxf(fmaxf(s[0][rr], s[1][rr]), fmaxf(s[2][rr], s[3][rr]));
      cm = fmaxf(cm, __shfl_xor(cm, 1));
      cm = fmaxf(cm, __shfl_xor(cm, 2));
      cm = fmaxf(cm, __shfl_xor(cm, 4));
      cm = fmaxf(cm, __shfl_xor(cm, 8));
      float mnew = fmaxf(m_i[rr], cm);
      float alpha = exp2f((m_i[rr] - mnew) * 1.44269504f);
      m_i[rr] = mnew;
      float ls = 0.f;
#pragma unroll
      for (int kt = 0; kt < 4; ++kt) {
        float p = exp2f((s[kt][rr] - mnew) * 1.44269504f);
        s[kt][rr] = p;
        ls += p;
      }
      ls += __shfl_xor(ls, 1);
      ls += __shfl_xor(ls, 2);
      ls += __shfl_xor(ls, 4);
      ls += __shfl_xor(ls, 8);
      l_i[rr] = l_i[rr] * alpha + ls;
#pragma unroll
      for (int nt = 0; nt < 4; ++nt) acc[nt][rr] *= alpha;
#pragma unroll
      for (int kt = 0; kt < 4; ++kt)
        Ps[wave][quad * 4 + rr][kt * 16 + l16] = (bf16)s[kt][rr];
    }

    // ---- PV: A[m=q=l16][k=key], B[n=dh=l16][k=key] (per-wave Ps region;
    //      in-wave DS ordering + compiler lgkmcnt covers the round trip) ----
    bf16x8 ap0 = *(const bf16x8*)&Ps[wave][l16][quad * 8];
    bf16x8 ap1 = *(const bf16x8*)&Ps[wave][l16][32 + quad * 8];
#pragma unroll
    for (int nt = 0; nt < 4; ++nt) {
      bf16x8 bv0 = *(const bf16x8*)&Vt[nt * 16 + l16][quad * 8];
      bf16x8 bv1 = *(const bf16x8*)&Vt[nt * 16 + l16][32 + quad * 8];
      acc[nt] = __builtin_amdgcn_mfma_f32_16x16x32_bf16(ap0, bv0, acc[nt], 0, 0, 0);
      acc[nt] = __builtin_amdgcn_mfma_f32_16x16x32_bf16(ap1, bv1, acc[nt], 0, 0, 0);
    }
  }

  // ---- epilogue: O = acc / l ----
#pragma unroll
  for (int nt = 0; nt < 4; ++nt) {
#pragma unroll
    for (int rr = 0; rr < 4; ++rr) {
      int qrow = qt * 64 + wave * 16 + quad * 4 + rr;
      float o = acc[nt][rr] / fmaxf(l_i[rr], 1e-20f);
      Ob[(size_t)qrow * D + nt * 16 + l16] = (bf16)o;
    }
  }
}

// ---------------------------------------------------------------------------
// out = LayerNorm(Y + X) * g + b.  Y bf16; X dtype TR; out dtype TO.
// ---------------------------------------------------------------------------
template <typename TR, typename TO>
__global__ __launch_bounds__(256) void k_add_ln(const bf16* __restrict__ Y,
                                                const TR* __restrict__ X,
                                                const float* __restrict__ g,
                                                const float* __restrict__ b,
                                                TO* __restrict__ out) {
  int wave = threadIdx.x >> 6, lane = threadIdx.x & 63;
  int row = blockIdx.x * 4 + wave;
  const bf16* y = Y + (size_t)row * 768;
  const TR* x = X + (size_t)row * 768;
  float v[12];
  float s = 0.f, s2 = 0.f;
#pragma unroll
  for (int c = 0; c < 3; ++c) {
    int idx = c * 256 + lane * 4;
    bf16x4 yv = *(const bf16x4*)(y + idx);
    float xv[4];
    if constexpr (__is_same(TR, float)) {
      float4 t = *(const float4*)(x + idx);
      xv[0] = t.x; xv[1] = t.y; xv[2] = t.z; xv[3] = t.w;
    } else {
      bf16x4 t = *(const bf16x4*)(x + idx);
#pragma unroll
      for (int i = 0; i < 4; ++i) xv[i] = (float)t[i];
    }
#pragma unroll
    for (int i = 0; i < 4; ++i) {
      float t = (float)yv[i] + xv[i];
      v[c * 4 + i] = t; s += t; s2 += t * t;
    }
  }
#pragma unroll
  for (int off = 32; off > 0; off >>= 1) { s += __shfl_xor(s, off); s2 += __shfl_xor(s2, off); }
  float mean = s * (1.f / 768.f);
  float var = s2 * (1.f / 768.f) - mean * mean;
  var = fmaxf(var, 0.f);
  float inv = rsqrtf(var + 1e-12f);
  TO* o = out + (size_t)row * 768;
#pragma unroll
  for (int c = 0; c < 3; ++c) {
    int idx = c * 256 + lane * 4;
    float4 gv = *(const float4*)(g + idx);
    float4 bv = *(const float4*)(b + idx);
    float r0 = (v[c * 4 + 0] - mean) * inv * gv.x + bv.x;
    float r1 = (v[c * 4 + 1] - mean) * inv * gv.y + bv.y;
    float r2 = (v[c * 4 + 2] - mean) * inv * gv.z + bv.z;
    float r3 = (v[c * 4 + 3] - mean) * inv * gv.w + bv.w;
    if constexpr (__is_same(TO, float)) {
      float4 ov = {r0, r1, r2, r3};
      *(float4*)(o + idx) = ov;
    } else {
      bf16x4 ov;
      ov[0] = (bf16)r0; ov[1] = (bf16)r1; ov[2] = (bf16)r2; ov[3] = (bf16)r3;
      *(bf16x4*)(o + idx) = ov;
    }
  }
}

// ---------------------------------------------------------------------------
extern "C" void kernel_launch(void* const* d_in, const int* in_sizes, int n_in,
                              void* d_out, int out_size, void* d_ws, size_t ws_size,
                              hipStream_t stream) {
  (void)in_sizes; (void)n_in; (void)out_size; (void)ws_size;
  const float* X     = (const float*)d_in[0];
  const float* tag   = (const float*)d_in[1];
  const float* sa_wq = (const float*)d_in[2];
  const float* sa_bq = (const float*)d_in[3];
  const float* sa_wk = (const float*)d_in[4];
  const float* sa_bk = (const float*)d_in[5];
  const float* sa_wv = (const float*)d_in[6];
  const float* sa_bv = (const float*)d_in[7];
  const float* sa_wo = (const float*)d_in[8];
  const float* sa_bo = (const float*)d_in[9];
  const float* sa_lg = (const float*)d_in[10];
  const float* sa_lb = (const float*)d_in[11];
  const float* ca_wq = (const float*)d_in[12];
  const float* ca_bq = (const float*)d_in[13];
  const float* ca_wk = (const float*)d_in[14];
  const float* ca_bk = (const float*)d_in[15];
  const float* ca_wv = (const float*)d_in[16];
  const float* ca_bv = (const float*)d_in[17];
  const float* ca_wo = (const float*)d_in[18];
  const float* ca_bo = (const float*)d_in[19];
  const float* ca_lg = (const float*)d_in[20];
  const float* ca_lb = (const float*)d_in[21];
  const float* ff_w1 = (const float*)d_in[22];
  const float* ff_b1 = (const float*)d_in[23];
  const float* ff_w2 = (const float*)d_in[24];
  const float* ff_b2 = (const float*)d_in[25];
  const float* ff_lg = (const float*)d_in[26];
  const float* ff_lb = (const float*)d_in[27];

  float* out = (float*)d_out;
  bf16* outb = (bf16*)d_out;  // fp32 out buffer doubles as bf16 ctx scratch
  const long long NTOK = (long long)4096 * 768;

  // ---- workspace: ~34.8 MB (all internal buffers bf16) ----
  const size_t SLOT = (size_t)4096 * 768;
  bf16* Xb     = (bf16*)d_ws;
  bf16* slotA  = Xb + SLOT;
  bf16* slotB  = slotA + SLOT;
  bf16* slotC  = slotB + SLOT;
  bf16* interC = slotC + SLOT;
  bf16* y3c    = interC + (size_t)1024 * 3072;
  bf16* Wt     = y3c + (size_t)1024 * 768;
  bf16* tagp   = Wt + (size_t)768 * 768;
  bf16* k2     = tagp + (size_t)128 * 768;
  bf16* v2     = k2 + (size_t)128 * 768;

  dim3 blk(256);
  const long long kvb_sa = (long long)2048 * 768;

  k_cvt<<<dim3(3072), blk, 0, stream>>>(X, Xb, NTOK);
  k_pad_tags<<<dim3(384), blk, 0, stream>>>(tag, tagp);

  // ---- self-attention ----
  k_transpose<<<dim3(12, 12), blk, 0, stream>>>(sa_wq, Wt, 768, 768);
  k_gemm<<<dim3(32, 6), blk, 0, stream>>>(Xb, Wt, sa_bq, slotA, 4096, 768, 768, 0);  // Q
  k_transpose<<<dim3(12, 12), blk, 0, stream>>>(sa_wk, Wt, 768, 768);
  k_gemm<<<dim3(32, 6), blk, 0, stream>>>(Xb, Wt, sa_bk, slotB, 4096, 768, 768, 0);  // K
  k_transpose<<<dim3(12, 12), blk, 0, stream>>>(sa_wv, Wt, 768, 768);
  k_gemm<<<dim3(32, 6), blk, 0, stream>>>(Xb, Wt, sa_bv, slotC, 4096, 768, 768, 0);  // V
  k_attn_mfma<<<dim3(32, 24), blk, 0, stream>>>(slotA, slotB, slotC, outb, 2048, 2048, kvb_sa, 50);
  k_transpose<<<dim3(12, 12), blk, 0, stream>>>(sa_wo, Wt, 768, 768);
  k_gemm<<<dim3(32, 6), blk, 0, stream>>>(outb, Wt, sa_bo, slotA, 4096, 768, 768, 0);   // y1
  k_add_ln<float, bf16><<<dim3(1024), blk, 0, stream>>>(slotA, X, sa_lg, sa_lb, slotA); // attn1

  // ---- cross-attention (64 tag keys, batch-shared) ----
  k_transpose<<<dim3(12, 12), blk, 0, stream>>>(ca_wq, Wt, 768, 768);
  k_gemm<<<dim3(32, 6), blk, 0, stream>>>(slotA, Wt, ca_bq, slotB, 4096, 768, 768, 0);  // Q2
  k_transpose<<<dim3(12, 12), blk, 0, stream>>>(ca_wk, Wt, 768, 768);
  k_gemm<<<dim3(1, 6), blk, 0, stream>>>(tagp, Wt, ca_bk, k2, 128, 768, 768, 0);        // K2
  k_transpose<<<dim3(12, 12), blk, 0, stream>>>(ca_wv, Wt, 768, 768);
  k_gemm<<<dim3(1, 6), blk, 0, stream>>>(tagp, Wt, ca_bv, v2, 128, 768, 768, 0);        // V2
  k_attn_mfma<<<dim3(32, 24), blk, 0, stream>>>(slotB, k2, v2, outb, 2048, 64, 0, -1);  // ctx2
  k_transpose<<<dim3(12, 12), blk, 0, stream>>>(ca_wo, Wt, 768, 768);
  k_gemm<<<dim3(32, 6), blk, 0, stream>>>(outb, Wt, ca_bo, slotB, 4096, 768, 768, 0);   // y2
  k_add_ln<bf16, bf16><<<dim3(1024), blk, 0, stream>>>(slotB, slotA, ca_lg, ca_lb, slotA); // attn2

  // ---- FFN, M-chunked (4 x 1024 rows), fused final add+LN per chunk ----
  k_transpose<<<dim3(48, 12), blk, 0, stream>>>(ff_w1, slotB, 768, 3072);  // ff1t [3072][768]
  k_transpose<<<dim3(12, 48), blk, 0, stream>>>(ff_w2, slotC, 3072, 768);  // ff2t [768][3072]
  for (int mc = 0; mc < 4; ++mc) {
    const bf16* a2 = slotA + (size_t)mc * 1024 * 768;
    k_gemm<<<dim3(8, 24), blk, 0, stream>>>(a2, slotB, ff_b1, interC, 1024, 3072, 768, 1);
    k_gemm<<<dim3(8, 6), blk, 0, stream>>>(interC, slotC, ff_b2, y3c, 1024, 768, 3072, 0);
    k_add_ln<bf16, float><<<dim3(256), blk, 0, stream>>>(y3c, a2, ff_lg, ff_lb,
                                                         out + (size_t)mc * 1024 * 768);
  }
}

// Round 7
// 598.698 us; speedup vs baseline: 27.4714x; 1.2687x over previous
//
#include <hip/hip_runtime.h>
#include <cstdint>
#include <cstddef>

// B=2, S=2048, D=768, H=12, DH=64, T=64, R=50, FF=3072
// fp32 I/O, bf16 MFMA internals.
// R6 bug: unchunked FFN1 (4096x3072) overflowed BIG (4096x2304) by exactly
// SLOT elems, clobbering slotA (attn2 residual) -> absmax 7.37.
// R7: identical to R6 except FFN runs in 2 M-chunks of 2048 rows via BIG.

typedef __bf16 bf16;
typedef __bf16 bf16x8 __attribute__((ext_vector_type(8)));
typedef __bf16 bf16x4 __attribute__((ext_vector_type(4)));
typedef float  floatx4 __attribute__((ext_vector_type(4)));

__device__ __forceinline__ void glds16(const bf16* g, bf16* l) {
  __builtin_amdgcn_global_load_lds((const __attribute__((address_space(1))) void*)g,
                                   (__attribute__((address_space(3))) void*)l, 16, 0, 0);
}

// ---------------------------------------------------------------------------
__global__ __launch_bounds__(256) void k_concat3(const float* __restrict__ a,
                                                 const float* __restrict__ b,
                                                 const float* __restrict__ c,
                                                 float* __restrict__ o, int seg) {
  int i = blockIdx.x * 256 + threadIdx.x;
  int s = i / seg, j = i - s * seg;
  const float* p = s == 0 ? a : (s == 1 ? b : c);
  o[i] = p[j];
}

__global__ void k_pad_tags(const float* __restrict__ tag, bf16* __restrict__ out) {
  int i = blockIdx.x * 256 + threadIdx.x;
  if (i < 64 * 768) out[i] = (bf16)tag[i];
  else if (i < 128 * 768) out[i] = (bf16)0.f;
}

// ---------------------------------------------------------------------------
__global__ __launch_bounds__(256) void k_transpose(const float* __restrict__ W,
                                                   bf16* __restrict__ Wt,
                                                   int K, int N) {
  __shared__ bf16 tile[64][72];
  int n0 = blockIdx.x * 64, k0 = blockIdx.y * 64;
  int t = threadIdx.x;
  int r = t >> 2, cg = (t & 3) * 16;
  const float* src = W + (size_t)(k0 + r) * N + n0 + cg;
  float tmp[16];
  *(float4*)&tmp[0]  = *(const float4*)(src);
  *(float4*)&tmp[4]  = *(const float4*)(src + 4);
  *(float4*)&tmp[8]  = *(const float4*)(src + 8);
  *(float4*)&tmp[12] = *(const float4*)(src + 12);
#pragma unroll
  for (int i = 0; i < 16; ++i) tile[r][cg + i] = (bf16)tmp[i];
  __syncthreads();
  bf16* dst = Wt + (size_t)(n0 + r) * K + k0 + cg;
#pragma unroll
  for (int g = 0; g < 2; ++g) {
    bf16x8 pack;
#pragma unroll
    for (int i = 0; i < 8; ++i) pack[i] = tile[cg + g * 8 + i][r];
    *(bf16x8*)(dst + g * 8) = pack;
  }
}

__global__ __launch_bounds__(256) void k_transpose4(const float* __restrict__ W0,
                                                    const float* __restrict__ W1,
                                                    const float* __restrict__ W2w,
                                                    const float* __restrict__ W3,
                                                    bf16* __restrict__ Wt) {
  __shared__ bf16 tile[64][72];
  int z = blockIdx.z;
  const float* W = z == 0 ? W0 : (z == 1 ? W1 : (z == 2 ? W2w : W3));
  bf16* dstb = Wt + (size_t)z * 768 * 768;
  int n0 = blockIdx.x * 64, k0 = blockIdx.y * 64;
  int t = threadIdx.x;
  int r = t >> 2, cg = (t & 3) * 16;
  const float* src = W + (size_t)(k0 + r) * 768 + n0 + cg;
  float tmp[16];
  *(float4*)&tmp[0]  = *(const float4*)(src);
  *(float4*)&tmp[4]  = *(const float4*)(src + 4);
  *(float4*)&tmp[8]  = *(const float4*)(src + 8);
  *(float4*)&tmp[12] = *(const float4*)(src + 12);
#pragma unroll
  for (int i = 0; i < 16; ++i) tile[r][cg + i] = (bf16)tmp[i];
  __syncthreads();
  bf16* dst = dstb + (size_t)(n0 + r) * 768 + k0 + cg;
#pragma unroll
  for (int g = 0; g < 2; ++g) {
    bf16x8 pack;
#pragma unroll
    for (int i = 0; i < 8; ++i) pack[i] = tile[cg + g * 8 + i][r];
    *(bf16x8*)(dst + g * 8) = pack;
  }
}

// ---------------------------------------------------------------------------
// GEMM: C[M,N] = A[M,K] @ Bt[N,K]^T + bias. 128x128 tile, BK=32.
// glds width-16 staging; AF32: fp32 A converted in regs; CF32: fp32 C out.
template <bool AF32, bool CF32>
__global__ __launch_bounds__(256) void k_gemm(const void* __restrict__ Av,
                                              const bf16* __restrict__ Bt,
                                              const float* __restrict__ bias,
                                              void* __restrict__ Cv,
                                              int M, int N, int K, int act) {
  __shared__ bf16 As[128 * 32];
  __shared__ bf16 Bs[128 * 32];
  int tid = threadIdx.x;
  int lane = tid & 63, wave = tid >> 6;
  int wm = wave & 1, wn = wave >> 1;
  int m0 = blockIdx.x * 128, n0 = blockIdx.y * 128;
  int arow = tid >> 2, acol = (tid & 3) * 8;
  int ldst = arow * 32 + acol;  // = tid*8 elems = tid*16 bytes (glds pattern)

  const bf16* Ab = (const bf16*)Av;
  const float* Af = (const float*)Av;
  const bf16* Ap = Ab + (size_t)(m0 + arow) * K + acol;
  const float* Apf = Af + (size_t)(m0 + arow) * K + acol;
  const bf16* Bp = Bt + (size_t)(n0 + arow) * K + acol;

  floatx4 acc[4][4];
#pragma unroll
  for (int i = 0; i < 4; ++i)
#pragma unroll
    for (int j = 0; j < 4; ++j) acc[i][j] = floatx4{0.f, 0.f, 0.f, 0.f};

  float4 p0a, p0b, p1a, p1b;
  if constexpr (AF32) {
    p0a = *(const float4*)(Apf);
    p0b = *(const float4*)(Apf + 4);
    p1a = *(const float4*)(Apf + (size_t)64 * K);
    p1b = *(const float4*)(Apf + (size_t)64 * K + 4);
  }

  for (int k = 0; k < K; k += 32) {
    __syncthreads();
    glds16(Bp + k, &Bs[ldst]);
    glds16(Bp + (size_t)64 * K + k, &Bs[ldst + 2048]);
    if constexpr (AF32) {
      bf16x8 c0, c1;
      c0[0] = (bf16)p0a.x; c0[1] = (bf16)p0a.y; c0[2] = (bf16)p0a.z; c0[3] = (bf16)p0a.w;
      c0[4] = (bf16)p0b.x; c0[5] = (bf16)p0b.y; c0[6] = (bf16)p0b.z; c0[7] = (bf16)p0b.w;
      c1[0] = (bf16)p1a.x; c1[1] = (bf16)p1a.y; c1[2] = (bf16)p1a.z; c1[3] = (bf16)p1a.w;
      c1[4] = (bf16)p1b.x; c1[5] = (bf16)p1b.y; c1[6] = (bf16)p1b.z; c1[7] = (bf16)p1b.w;
      *(bf16x8*)&As[ldst] = c0;
      *(bf16x8*)&As[ldst + 2048] = c1;
    } else {
      glds16(Ap + k, &As[ldst]);
      glds16(Ap + (size_t)64 * K + k, &As[ldst + 2048]);
    }
    __syncthreads();
    if constexpr (AF32) {
      if (k + 32 < K) {
        p0a = *(const float4*)(Apf + k + 32);
        p0b = *(const float4*)(Apf + k + 36);
        p1a = *(const float4*)(Apf + (size_t)64 * K + k + 32);
        p1b = *(const float4*)(Apf + (size_t)64 * K + k + 36);
      }
    }
    bf16x8 a_frag[4], b_frag[4];
#pragma unroll
    for (int mt = 0; mt < 4; ++mt)
      a_frag[mt] = *(const bf16x8*)&As[(wm * 64 + mt * 16 + (lane & 15)) * 32 + (lane >> 4) * 8];
#pragma unroll
    for (int nt = 0; nt < 4; ++nt)
      b_frag[nt] = *(const bf16x8*)&Bs[(wn * 64 + nt * 16 + (lane & 15)) * 32 + (lane >> 4) * 8];
#pragma unroll
    for (int mt = 0; mt < 4; ++mt)
#pragma unroll
      for (int nt = 0; nt < 4; ++nt)
        acc[mt][nt] = __builtin_amdgcn_mfma_f32_16x16x32_bf16(a_frag[mt], b_frag[nt], acc[mt][nt], 0, 0, 0);
  }

#pragma unroll
  for (int nt = 0; nt < 4; ++nt) {
    int col = n0 + wn * 64 + nt * 16 + (lane & 15);
    float bv = bias[col];
#pragma unroll
    for (int mt = 0; mt < 4; ++mt) {
#pragma unroll
      for (int r = 0; r < 4; ++r) {
        int row = m0 + wm * 64 + mt * 16 + (lane >> 4) * 4 + r;
        float v = acc[mt][nt][r] + bv;
        if (act) v = 0.5f * v * (1.f + erff(v * 0.70710678118654752f));
        if constexpr (CF32) ((float*)Cv)[(size_t)row * N + col] = v;
        else ((bf16*)Cv)[(size_t)row * N + col] = (bf16)v;
      }
    }
  }
}

// ---------------------------------------------------------------------------
// MFMA flash attention, max-free streaming softmax; conflict-swizzled LDS.
__global__ __launch_bounds__(256) void k_attn_mfma(const bf16* __restrict__ Q, int ldq,
                                                   const bf16* __restrict__ Kp,
                                                   const bf16* __restrict__ Vp, int ldkv,
                                                   bf16* __restrict__ O,
                                                   int S, int Skv,
                                                   long long kv_bstride, int bandR) {
  const int NH = 12;
  int qt = blockIdx.x, bh = blockIdx.y;
  int bb = bh / NH, h = bh % NH;
  const bf16* Qb = Q + (size_t)bb * S * ldq + h * 64;
  const bf16* Kb = Kp + (size_t)bb * kv_bstride + h * 64;
  const bf16* Vb = Vp + (size_t)bb * kv_bstride + h * 64;
  bf16* Ob = O + (size_t)bb * S * 768 + h * 64;

  __shared__ bf16 Qs[64][72];
  __shared__ bf16 Ks[64][72];
  __shared__ bf16 Vt[64][72];
  __shared__ bf16 Ps[4][16][72];

  int tid = threadIdx.x, wave = tid >> 6, lane = tid & 63;
  int quad = lane >> 4, l16 = lane & 15;
  int r = tid >> 2, cg = (tid & 3) * 16, c4 = tid & 3;

  {
    const bf16* src = Qb + (size_t)(qt * 64 + r) * ldq + cg;
    *(bf16x8*)&Qs[r][cg] = *(const bf16x8*)src;
    *(bf16x8*)&Qs[r][cg + 8] = *(const bf16x8*)(src + 8);
  }

  float l_part[4] = {0.f, 0.f, 0.f, 0.f};
  floatx4 acc[4];
#pragma unroll
  for (int i = 0; i < 4; ++i) acc[i] = floatx4{0.f, 0.f, 0.f, 0.f};

  const float C1 = 0.18033688f;   // log2(e)/8
  const float C2 = 1.44269504f;   // log2(e) (the +1 band mask)

  for (int kc = 0; kc < Skv; kc += 64) {
    __syncthreads();
    {
      const bf16* ksrc = Kb + (size_t)(kc + r) * ldkv + cg;
      *(bf16x8*)&Ks[r][cg] = *(const bf16x8*)ksrc;
      *(bf16x8*)&Ks[r][cg + 8] = *(const bf16x8*)(ksrc + 8);
      const bf16* vsrc = Vb + (size_t)(kc + r) * ldkv + cg;
      bf16x8 w0 = *(const bf16x8*)vsrc;
      bf16x8 w1 = *(const bf16x8*)(vsrc + 8);
      int colw = (r + 16 * c4) & 63;  // Vt[d][(key+16*(d>>4))&63]
#pragma unroll
      for (int e = 0; e < 8; ++e) Vt[cg + e][colw] = w0[e];
#pragma unroll
      for (int e = 0; e < 8; ++e) Vt[cg + 8 + e][colw] = w1[e];
    }
    __syncthreads();

    bf16x8 aq0 = *(const bf16x8*)&Qs[wave * 16 + l16][quad * 8];
    bf16x8 aq1 = *(const bf16x8*)&Qs[wave * 16 + l16][32 + quad * 8];
    floatx4 s[4];
#pragma unroll
    for (int kt = 0; kt < 4; ++kt) {
      bf16x8 bk0 = *(const bf16x8*)&Ks[kt * 16 + l16][quad * 8];
      bf16x8 bk1 = *(const bf16x8*)&Ks[kt * 16 + l16][32 + quad * 8];
      floatx4 c = {0.f, 0.f, 0.f, 0.f};
      c = __builtin_amdgcn_mfma_f32_16x16x32_bf16(aq0, bk0, c, 0, 0, 0);
      c = __builtin_amdgcn_mfma_f32_16x16x32_bf16(aq1, bk1, c, 0, 0, 0);
      s[kt] = c;
    }

#pragma unroll
    for (int kt = 0; kt < 4; ++kt) {
      int kj = kc + kt * 16 + l16;
      int colp = ((kt + quad) & 3) * 16 + l16;
#pragma unroll
      for (int rr = 0; rr < 4; ++rr) {
        float e;
        if (bandR >= 0) {
          int qi = qt * 64 + wave * 16 + quad * 4 + rr;
          int d = qi - kj; if (d < 0) d = -d;
          e = exp2f(s[kt][rr] * C1 + (d <= bandR ? C2 : 0.f));
        } else {
          e = exp2f(s[kt][rr] * C1);
        }
        l_part[rr] += e;
        Ps[wave][quad * 4 + rr][colp] = (bf16)e;
      }
    }

    int qw = l16 >> 2, half = (quad & 1) * 8;
    int kt0 = quad >> 1, kt1 = 2 + (quad >> 1);
    bf16x8 ap0 = *(const bf16x8*)&Ps[wave][l16][((kt0 + qw) & 3) * 16 + half];
    bf16x8 ap1 = *(const bf16x8*)&Ps[wave][l16][((kt1 + qw) & 3) * 16 + half];
#pragma unroll
    for (int nt = 0; nt < 4; ++nt) {
      bf16x8 bv0 = *(const bf16x8*)&Vt[nt * 16 + l16][(quad * 8 + 16 * nt) & 63];
      bf16x8 bv1 = *(const bf16x8*)&Vt[nt * 16 + l16][(32 + quad * 8 + 16 * nt) & 63];
      acc[nt] = __builtin_amdgcn_mfma_f32_16x16x32_bf16(ap0, bv0, acc[nt], 0, 0, 0);
      acc[nt] = __builtin_amdgcn_mfma_f32_16x16x32_bf16(ap1, bv1, acc[nt], 0, 0, 0);
    }
  }

  float l[4];
#pragma unroll
  for (int rr = 0; rr < 4; ++rr) {
    float t = l_part[rr];
    t += __shfl_xor(t, 1);
    t += __shfl_xor(t, 2);
    t += __shfl_xor(t, 4);
    t += __shfl_xor(t, 8);
    l[rr] = t;
  }
#pragma unroll
  for (int nt = 0; nt < 4; ++nt) {
#pragma unroll
    for (int rr = 0; rr < 4; ++rr) {
      int qrow = qt * 64 + wave * 16 + quad * 4 + rr;
      Ob[(size_t)qrow * 768 + nt * 16 + l16] = (bf16)(acc[nt][rr] / l[rr]);
    }
  }
}

// ---------------------------------------------------------------------------
template <typename TY, typename TR, typename TO>
__global__ __launch_bounds__(256) void k_add_ln(const TY* __restrict__ Y,
                                                const TR* __restrict__ X,
                                                const float* __restrict__ g,
                                                const float* __restrict__ b,
                                                TO* __restrict__ out) {
  int wave = threadIdx.x >> 6, lane = threadIdx.x & 63;
  int row = blockIdx.x * 4 + wave;
  const TY* y = Y + (size_t)row * 768;
  const TR* x = X + (size_t)row * 768;
  float v[12];
  float s = 0.f, s2 = 0.f;
#pragma unroll
  for (int c = 0; c < 3; ++c) {
    int idx = c * 256 + lane * 4;
    float yv[4], xv[4];
    if constexpr (__is_same(TY, float)) {
      float4 t = *(const float4*)(y + idx);
      yv[0] = t.x; yv[1] = t.y; yv[2] = t.z; yv[3] = t.w;
    } else {
      bf16x4 t = *(const bf16x4*)(y + idx);
#pragma unroll
      for (int i = 0; i < 4; ++i) yv[i] = (float)t[i];
    }
    if constexpr (__is_same(TR, float)) {
      float4 t = *(const float4*)(x + idx);
      xv[0] = t.x; xv[1] = t.y; xv[2] = t.z; xv[3] = t.w;
    } else {
      bf16x4 t = *(const bf16x4*)(x + idx);
#pragma unroll
      for (int i = 0; i < 4; ++i) xv[i] = (float)t[i];
    }
#pragma unroll
    for (int i = 0; i < 4; ++i) {
      float t = yv[i] + xv[i];
      v[c * 4 + i] = t; s += t; s2 += t * t;
    }
  }
#pragma unroll
  for (int off = 32; off > 0; off >>= 1) { s += __shfl_xor(s, off); s2 += __shfl_xor(s2, off); }
  float mean = s * (1.f / 768.f);
  float var = fmaxf(s2 * (1.f / 768.f) - mean * mean, 0.f);
  float inv = rsqrtf(var + 1e-12f);
  TO* o = out + (size_t)row * 768;
#pragma unroll
  for (int c = 0; c < 3; ++c) {
    int idx = c * 256 + lane * 4;
    float4 gv = *(const float4*)(g + idx);
    float4 bv = *(const float4*)(b + idx);
    float r0 = (v[c * 4 + 0] - mean) * inv * gv.x + bv.x;
    float r1 = (v[c * 4 + 1] - mean) * inv * gv.y + bv.y;
    float r2 = (v[c * 4 + 2] - mean) * inv * gv.z + bv.z;
    float r3 = (v[c * 4 + 3] - mean) * inv * gv.w + bv.w;
    if constexpr (__is_same(TO, float)) {
      float4 ov = {r0, r1, r2, r3};
      *(float4*)(o + idx) = ov;
    } else {
      bf16x4 ov;
      ov[0] = (bf16)r0; ov[1] = (bf16)r1; ov[2] = (bf16)r2; ov[3] = (bf16)r3;
      *(bf16x4*)(o + idx) = ov;
    }
  }
}

// ---------------------------------------------------------------------------
extern "C" void kernel_launch(void* const* d_in, const int* in_sizes, int n_in,
                              void* d_out, int out_size, void* d_ws, size_t ws_size,
                              hipStream_t stream) {
  (void)in_sizes; (void)n_in; (void)out_size; (void)ws_size;
  const float* X     = (const float*)d_in[0];
  const float* tag   = (const float*)d_in[1];
  const float* sa_wq = (const float*)d_in[2];
  const float* sa_bq = (const float*)d_in[3];
  const float* sa_wk = (const float*)d_in[4];
  const float* sa_bk = (const float*)d_in[5];
  const float* sa_wv = (const float*)d_in[6];
  const float* sa_bv = (const float*)d_in[7];
  const float* sa_wo = (const float*)d_in[8];
  const float* sa_bo = (const float*)d_in[9];
  const float* sa_lg = (const float*)d_in[10];
  const float* sa_lb = (const float*)d_in[11];
  const float* ca_wq = (const float*)d_in[12];
  const float* ca_bq = (const float*)d_in[13];
  const float* ca_wk = (const float*)d_in[14];
  const float* ca_bk = (const float*)d_in[15];
  const float* ca_wv = (const float*)d_in[16];
  const float* ca_bv = (const float*)d_in[17];
  const float* ca_wo = (const float*)d_in[18];
  const float* ca_bo = (const float*)d_in[19];
  const float* ca_lg = (const float*)d_in[20];
  const float* ca_lb = (const float*)d_in[21];
  const float* ff_w1 = (const float*)d_in[22];
  const float* ff_b1 = (const float*)d_in[23];
  const float* ff_w2 = (const float*)d_in[24];
  const float* ff_b2 = (const float*)d_in[25];
  const float* ff_lg = (const float*)d_in[26];
  const float* ff_lb = (const float*)d_in[27];

  float* outf = (float*)d_out;
  bf16* outb = (bf16*)d_out;
  const size_t SLOT = (size_t)4096 * 768;

  // ---- ws: 34.60 MB ----
  bf16* BIG   = (bf16*)d_ws;                    // 4096x2304
  bf16* slotA = BIG + (size_t)4096 * 2304;      // residual chain
  bf16* Wall  = slotA + SLOT;                   // 3072x768
  bf16* W2    = Wall + (size_t)3072 * 768;      // 768x3072
  bf16* tagp  = W2;
  bf16* k2v2  = W2 + (size_t)128 * 768;
  float* bQKV = (float*)(W2 + (size_t)128 * 768 + (size_t)128 * 1536);
  float* bKV2 = bQKV + 2304;

  dim3 blk(256);

  k_concat3<<<dim3(9), blk, 0, stream>>>(sa_bq, sa_bk, sa_bv, bQKV, 768);
  k_concat3<<<dim3(6), blk, 0, stream>>>(ca_bk, ca_bv, nullptr, bKV2, 768);
  k_pad_tags<<<dim3(384), blk, 0, stream>>>(tag, tagp);

  // ---- self-attention ----
  k_transpose4<<<dim3(12, 12, 4), blk, 0, stream>>>(sa_wq, sa_wk, sa_wv, sa_wo, Wall);
  k_gemm<true, false><<<dim3(32, 18), blk, 0, stream>>>(X, Wall, bQKV, BIG,
                                                        4096, 2304, 768, 0);  // QKV
  k_attn_mfma<<<dim3(32, 24), blk, 0, stream>>>(BIG, 2304, BIG + 768, BIG + 1536, 2304,
                                                outb, 2048, 2048, (long long)2048 * 2304, 50);
  k_gemm<false, false><<<dim3(32, 6), blk, 0, stream>>>(outb, Wall + (size_t)2304 * 768,
                                                        sa_bo, slotA, 4096, 768, 768, 0);  // y1
  k_add_ln<bf16, float, bf16><<<dim3(1024), blk, 0, stream>>>(slotA, X, sa_lg, sa_lb, slotA);

  // ---- cross-attention ----
  k_transpose4<<<dim3(12, 12, 4), blk, 0, stream>>>(ca_wq, ca_wk, ca_wv, ca_wo, Wall);
  k_gemm<false, false><<<dim3(32, 6), blk, 0, stream>>>(slotA, Wall, ca_bq, BIG,
                                                        4096, 768, 768, 0);  // Q2
  k_gemm<false, false><<<dim3(1, 12), blk, 0, stream>>>(tagp, Wall + (size_t)768 * 768,
                                                        bKV2, k2v2, 128, 1536, 768, 0);  // K2V2
  k_attn_mfma<<<dim3(32, 24), blk, 0, stream>>>(BIG, 768, k2v2, k2v2 + 768, 1536,
                                                outb, 2048, 64, 0, -1);
  k_gemm<false, false><<<dim3(32, 6), blk, 0, stream>>>(outb, Wall + (size_t)2304 * 768,
                                                        ca_bo, BIG + SLOT, 4096, 768, 768, 0);  // y2
  k_add_ln<bf16, bf16, bf16><<<dim3(1024), blk, 0, stream>>>(BIG + SLOT, slotA, ca_lg, ca_lb, slotA);

  // ---- FFN: 2 M-chunks of 2048 rows via BIG (2048x3072 = 12.6MB <= BIG) ----
  k_transpose<<<dim3(48, 12), blk, 0, stream>>>(ff_w1, Wall, 768, 3072);  // ff1t [3072][768]
  k_transpose<<<dim3(12, 48), blk, 0, stream>>>(ff_w2, W2, 3072, 768);    // ff2t [768][3072]
  for (int mc = 0; mc < 2; ++mc) {
    const bf16* a2 = slotA + (size_t)mc * 2048 * 768;
    float* yo = outf + (size_t)mc * 2048 * 768;
    k_gemm<false, false><<<dim3(16, 24), blk, 0, stream>>>(a2, Wall, ff_b1, BIG,
                                                           2048, 3072, 768, 1);  // gelu inter
    k_gemm<false, true><<<dim3(16, 6), blk, 0, stream>>>(BIG, W2, ff_b2, yo,
                                                         2048, 768, 3072, 0);    // y3 fp32
    k_add_ln<float, bf16, float><<<dim3(512), blk, 0, stream>>>(yo, a2, ff_lg, ff_lb, yo);
  }
}

// Round 8
// 512.830 us; speedup vs baseline: 32.0711x; 1.1674x over previous
//
#include <hip/hip_runtime.h>
#include <cstdint>
#include <cstddef>

// B=2, S=2048, D=768, H=12, DH=64, T=64, R=50, FF=3072
// fp32 I/O, bf16 MFMA internals.
// R8: (1) BM=64 GEMM tile for N=768 GEMMs (grid 192->384 blocks; R7 showed
// those run at 0.75 blocks/CU); (2) attention: hoisted Q fragments + band-mask
// chunk skip (VALUBusy 50% was exp/mask/addr VALU); LDS conflicts are at the
// b128 structural floor per R7 analysis -- no further swizzling.

typedef __bf16 bf16;
typedef __bf16 bf16x8 __attribute__((ext_vector_type(8)));
typedef __bf16 bf16x4 __attribute__((ext_vector_type(4)));
typedef float  floatx4 __attribute__((ext_vector_type(4)));

__device__ __forceinline__ void glds16(const bf16* g, bf16* l) {
  __builtin_amdgcn_global_load_lds((const __attribute__((address_space(1))) void*)g,
                                   (__attribute__((address_space(3))) void*)l, 16, 0, 0);
}

// ---------------------------------------------------------------------------
__global__ __launch_bounds__(256) void k_concat3(const float* __restrict__ a,
                                                 const float* __restrict__ b,
                                                 const float* __restrict__ c,
                                                 float* __restrict__ o, int seg) {
  int i = blockIdx.x * 256 + threadIdx.x;
  int s = i / seg, j = i - s * seg;
  const float* p = s == 0 ? a : (s == 1 ? b : c);
  o[i] = p[j];
}

__global__ void k_pad_tags(const float* __restrict__ tag, bf16* __restrict__ out) {
  int i = blockIdx.x * 256 + threadIdx.x;
  if (i < 64 * 768) out[i] = (bf16)tag[i];
  else if (i < 128 * 768) out[i] = (bf16)0.f;
}

// ---------------------------------------------------------------------------
__global__ __launch_bounds__(256) void k_transpose(const float* __restrict__ W,
                                                   bf16* __restrict__ Wt,
                                                   int K, int N) {
  __shared__ bf16 tile[64][72];
  int n0 = blockIdx.x * 64, k0 = blockIdx.y * 64;
  int t = threadIdx.x;
  int r = t >> 2, cg = (t & 3) * 16;
  const float* src = W + (size_t)(k0 + r) * N + n0 + cg;
  float tmp[16];
  *(float4*)&tmp[0]  = *(const float4*)(src);
  *(float4*)&tmp[4]  = *(const float4*)(src + 4);
  *(float4*)&tmp[8]  = *(const float4*)(src + 8);
  *(float4*)&tmp[12] = *(const float4*)(src + 12);
#pragma unroll
  for (int i = 0; i < 16; ++i) tile[r][cg + i] = (bf16)tmp[i];
  __syncthreads();
  bf16* dst = Wt + (size_t)(n0 + r) * K + k0 + cg;
#pragma unroll
  for (int g = 0; g < 2; ++g) {
    bf16x8 pack;
#pragma unroll
    for (int i = 0; i < 8; ++i) pack[i] = tile[cg + g * 8 + i][r];
    *(bf16x8*)(dst + g * 8) = pack;
  }
}

__global__ __launch_bounds__(256) void k_transpose4(const float* __restrict__ W0,
                                                    const float* __restrict__ W1,
                                                    const float* __restrict__ W2w,
                                                    const float* __restrict__ W3,
                                                    bf16* __restrict__ Wt) {
  __shared__ bf16 tile[64][72];
  int z = blockIdx.z;
  const float* W = z == 0 ? W0 : (z == 1 ? W1 : (z == 2 ? W2w : W3));
  bf16* dstb = Wt + (size_t)z * 768 * 768;
  int n0 = blockIdx.x * 64, k0 = blockIdx.y * 64;
  int t = threadIdx.x;
  int r = t >> 2, cg = (t & 3) * 16;
  const float* src = W + (size_t)(k0 + r) * 768 + n0 + cg;
  float tmp[16];
  *(float4*)&tmp[0]  = *(const float4*)(src);
  *(float4*)&tmp[4]  = *(const float4*)(src + 4);
  *(float4*)&tmp[8]  = *(const float4*)(src + 8);
  *(float4*)&tmp[12] = *(const float4*)(src + 12);
#pragma unroll
  for (int i = 0; i < 16; ++i) tile[r][cg + i] = (bf16)tmp[i];
  __syncthreads();
  bf16* dst = dstb + (size_t)(n0 + r) * 768 + k0 + cg;
#pragma unroll
  for (int g = 0; g < 2; ++g) {
    bf16x8 pack;
#pragma unroll
    for (int i = 0; i < 8; ++i) pack[i] = tile[cg + g * 8 + i][r];
    *(bf16x8*)(dst + g * 8) = pack;
  }
}

// ---------------------------------------------------------------------------
// GEMM: C[M,N] = A[M,K] @ Bt[N,K]^T + bias. BMx128 tile (BM in {64,128}),
// BK=32, glds width-16 staging. 4 waves 2x2; wave covers (BM/2)x64.
// AF32: fp32 A cvt in regs (BM=128 only). CF32: fp32 C out.
template <int BM, bool AF32, bool CF32>
__global__ __launch_bounds__(256) void k_gemm(const void* __restrict__ Av,
                                              const bf16* __restrict__ Bt,
                                              const float* __restrict__ bias,
                                              void* __restrict__ Cv,
                                              int M, int N, int K, int act) {
  constexpr int MT = BM / 32;  // m-tiles per wave: 128->4, 64->2
  __shared__ bf16 As[BM * 32];
  __shared__ bf16 Bs[128 * 32];
  int tid = threadIdx.x;
  int lane = tid & 63, wave = tid >> 6;
  int l16 = lane & 15, quad = lane >> 4;
  int wm = wave & 1, wn = wave >> 1;
  int m0 = blockIdx.x * BM, n0 = blockIdx.y * 128;
  int arow = tid >> 2, acol = (tid & 3) * 8;
  int ldst = arow * 32 + acol;  // = tid*8 elems (lane-contiguous glds pattern)

  const bf16* Ab = (const bf16*)Av;
  const float* Af = (const float*)Av;
  const bf16* Ap = Ab + (size_t)(m0 + arow) * K + acol;
  const float* Apf = Af + (size_t)(m0 + arow) * K + acol;
  const bf16* Bp = Bt + (size_t)(n0 + arow) * K + acol;

  floatx4 acc[MT][4];
#pragma unroll
  for (int i = 0; i < MT; ++i)
#pragma unroll
    for (int j = 0; j < 4; ++j) acc[i][j] = floatx4{0.f, 0.f, 0.f, 0.f};

  float4 p0a, p0b, p1a, p1b;
  if constexpr (AF32) {
    p0a = *(const float4*)(Apf);
    p0b = *(const float4*)(Apf + 4);
    p1a = *(const float4*)(Apf + (size_t)64 * K);
    p1b = *(const float4*)(Apf + (size_t)64 * K + 4);
  }

  for (int k = 0; k < K; k += 32) {
    __syncthreads();
    glds16(Bp + k, &Bs[ldst]);
    glds16(Bp + (size_t)64 * K + k, &Bs[ldst + 2048]);
    if constexpr (AF32) {
      bf16x8 c0, c1;
      c0[0] = (bf16)p0a.x; c0[1] = (bf16)p0a.y; c0[2] = (bf16)p0a.z; c0[3] = (bf16)p0a.w;
      c0[4] = (bf16)p0b.x; c0[5] = (bf16)p0b.y; c0[6] = (bf16)p0b.z; c0[7] = (bf16)p0b.w;
      c1[0] = (bf16)p1a.x; c1[1] = (bf16)p1a.y; c1[2] = (bf16)p1a.z; c1[3] = (bf16)p1a.w;
      c1[4] = (bf16)p1b.x; c1[5] = (bf16)p1b.y; c1[6] = (bf16)p1b.z; c1[7] = (bf16)p1b.w;
      *(bf16x8*)&As[ldst] = c0;
      *(bf16x8*)&As[ldst + 2048] = c1;
    } else {
      glds16(Ap + k, &As[ldst]);
      if constexpr (BM == 128) glds16(Ap + (size_t)64 * K + k, &As[ldst + 2048]);
    }
    __syncthreads();
    if constexpr (AF32) {
      if (k + 32 < K) {
        p0a = *(const float4*)(Apf + k + 32);
        p0b = *(const float4*)(Apf + k + 36);
        p1a = *(const float4*)(Apf + (size_t)64 * K + k + 32);
        p1b = *(const float4*)(Apf + (size_t)64 * K + k + 36);
      }
    }
    bf16x8 a_frag[MT], b_frag[4];
#pragma unroll
    for (int mt = 0; mt < MT; ++mt)
      a_frag[mt] = *(const bf16x8*)&As[(wm * (BM / 2) + mt * 16 + l16) * 32 + quad * 8];
#pragma unroll
    for (int nt = 0; nt < 4; ++nt)
      b_frag[nt] = *(const bf16x8*)&Bs[(wn * 64 + nt * 16 + l16) * 32 + quad * 8];
#pragma unroll
    for (int mt = 0; mt < MT; ++mt)
#pragma unroll
      for (int nt = 0; nt < 4; ++nt)
        acc[mt][nt] = __builtin_amdgcn_mfma_f32_16x16x32_bf16(a_frag[mt], b_frag[nt], acc[mt][nt], 0, 0, 0);
  }

#pragma unroll
  for (int nt = 0; nt < 4; ++nt) {
    int col = n0 + wn * 64 + nt * 16 + l16;
    float bv = bias[col];
#pragma unroll
    for (int mt = 0; mt < MT; ++mt) {
#pragma unroll
      for (int r = 0; r < 4; ++r) {
        int row = m0 + wm * (BM / 2) + mt * 16 + quad * 4 + r;
        float v = acc[mt][nt][r] + bv;
        if (act) v = 0.5f * v * (1.f + erff(v * 0.70710678118654752f));
        if constexpr (CF32) ((float*)Cv)[(size_t)row * N + col] = v;
        else ((bf16*)Cv)[(size_t)row * N + col] = (bf16)v;
      }
    }
  }
}

// ---------------------------------------------------------------------------
// MFMA flash attention, max-free streaming softmax; conflict-swizzled LDS.
// R8: Q fragments hoisted out of K-loop; band-mask math only on the ~3/32
// chunks that overlap the band (block-uniform branch).
__global__ __launch_bounds__(256) void k_attn_mfma(const bf16* __restrict__ Q, int ldq,
                                                   const bf16* __restrict__ Kp,
                                                   const bf16* __restrict__ Vp, int ldkv,
                                                   bf16* __restrict__ O,
                                                   int S, int Skv,
                                                   long long kv_bstride, int bandR) {
  const int NH = 12;
  int qt = blockIdx.x, bh = blockIdx.y;
  int bb = bh / NH, h = bh % NH;
  const bf16* Qb = Q + (size_t)bb * S * ldq + h * 64;
  const bf16* Kb = Kp + (size_t)bb * kv_bstride + h * 64;
  const bf16* Vb = Vp + (size_t)bb * kv_bstride + h * 64;
  bf16* Ob = O + (size_t)bb * S * 768 + h * 64;

  __shared__ bf16 Qs[64][72];
  __shared__ bf16 Ks[64][72];
  __shared__ bf16 Vt[64][72];
  __shared__ bf16 Ps[4][16][72];

  int tid = threadIdx.x, wave = tid >> 6, lane = tid & 63;
  int quad = lane >> 4, l16 = lane & 15;
  int r = tid >> 2, cg = (tid & 3) * 16, c4 = tid & 3;

  {
    const bf16* src = Qb + (size_t)(qt * 64 + r) * ldq + cg;
    *(bf16x8*)&Qs[r][cg] = *(const bf16x8*)src;
    *(bf16x8*)&Qs[r][cg + 8] = *(const bf16x8*)(src + 8);
  }
  __syncthreads();
  // Q fragments are loop-invariant: load once (Qs never rewritten).
  bf16x8 aq0 = *(const bf16x8*)&Qs[wave * 16 + l16][quad * 8];
  bf16x8 aq1 = *(const bf16x8*)&Qs[wave * 16 + l16][32 + quad * 8];

  float l_part[4] = {0.f, 0.f, 0.f, 0.f};
  floatx4 acc[4];
#pragma unroll
  for (int i = 0; i < 4; ++i) acc[i] = floatx4{0.f, 0.f, 0.f, 0.f};

  const float C1 = 0.18033688f;   // log2(e)/8
  const float C2 = 1.44269504f;   // log2(e) (the +1 band mask)
  int qi_base = qt * 64 + wave * 16 + quad * 4;

  for (int kc = 0; kc < Skv; kc += 64) {
    __syncthreads();
    {
      const bf16* ksrc = Kb + (size_t)(kc + r) * ldkv + cg;
      *(bf16x8*)&Ks[r][cg] = *(const bf16x8*)ksrc;
      *(bf16x8*)&Ks[r][cg + 8] = *(const bf16x8*)(ksrc + 8);
      const bf16* vsrc = Vb + (size_t)(kc + r) * ldkv + cg;
      bf16x8 w0 = *(const bf16x8*)vsrc;
      bf16x8 w1 = *(const bf16x8*)(vsrc + 8);
      int colw = (r + 16 * c4) & 63;  // Vt[d][(key+16*(d>>4))&63]
#pragma unroll
      for (int e = 0; e < 8; ++e) Vt[cg + e][colw] = w0[e];
#pragma unroll
      for (int e = 0; e < 8; ++e) Vt[cg + 8 + e][colw] = w1[e];
    }
    __syncthreads();

    floatx4 s[4];
#pragma unroll
    for (int kt = 0; kt < 4; ++kt) {
      bf16x8 bk0 = *(const bf16x8*)&Ks[kt * 16 + l16][quad * 8];
      bf16x8 bk1 = *(const bf16x8*)&Ks[kt * 16 + l16][32 + quad * 8];
      floatx4 c = {0.f, 0.f, 0.f, 0.f};
      c = __builtin_amdgcn_mfma_f32_16x16x32_bf16(aq0, bk0, c, 0, 0, 0);
      c = __builtin_amdgcn_mfma_f32_16x16x32_bf16(aq1, bk1, c, 0, 0, 0);
      s[kt] = c;
    }

    // block-uniform: does this chunk intersect the band at all?
    bool masked = (bandR >= 0) && (kc <= qt * 64 + 63 + bandR) &&
                  (kc + 63 >= qt * 64 - bandR);
    if (masked) {
#pragma unroll
      for (int kt = 0; kt < 4; ++kt) {
        int kj = kc + kt * 16 + l16;
        int colp = ((kt + quad) & 3) * 16 + l16;
#pragma unroll
        for (int rr = 0; rr < 4; ++rr) {
          int d = qi_base + rr - kj; if (d < 0) d = -d;
          float e = exp2f(s[kt][rr] * C1 + (d <= bandR ? C2 : 0.f));
          l_part[rr] += e;
          Ps[wave][quad * 4 + rr][colp] = (bf16)e;
        }
      }
    } else {
#pragma unroll
      for (int kt = 0; kt < 4; ++kt) {
        int colp = ((kt + quad) & 3) * 16 + l16;
#pragma unroll
        for (int rr = 0; rr < 4; ++rr) {
          float e = exp2f(s[kt][rr] * C1);
          l_part[rr] += e;
          Ps[wave][quad * 4 + rr][colp] = (bf16)e;
        }
      }
    }

    int qw = l16 >> 2, half = (quad & 1) * 8;
    int kt0 = quad >> 1, kt1 = 2 + (quad >> 1);
    bf16x8 ap0 = *(const bf16x8*)&Ps[wave][l16][((kt0 + qw) & 3) * 16 + half];
    bf16x8 ap1 = *(const bf16x8*)&Ps[wave][l16][((kt1 + qw) & 3) * 16 + half];
#pragma unroll
    for (int nt = 0; nt < 4; ++nt) {
      bf16x8 bv0 = *(const bf16x8*)&Vt[nt * 16 + l16][(quad * 8 + 16 * nt) & 63];
      bf16x8 bv1 = *(const bf16x8*)&Vt[nt * 16 + l16][(32 + quad * 8 + 16 * nt) & 63];
      acc[nt] = __builtin_amdgcn_mfma_f32_16x16x32_bf16(ap0, bv0, acc[nt], 0, 0, 0);
      acc[nt] = __builtin_amdgcn_mfma_f32_16x16x32_bf16(ap1, bv1, acc[nt], 0, 0, 0);
    }
  }

  float l[4];
#pragma unroll
  for (int rr = 0; rr < 4; ++rr) {
    float t = l_part[rr];
    t += __shfl_xor(t, 1);
    t += __shfl_xor(t, 2);
    t += __shfl_xor(t, 4);
    t += __shfl_xor(t, 8);
    l[rr] = t;
  }
#pragma unroll
  for (int nt = 0; nt < 4; ++nt) {
#pragma unroll
    for (int rr = 0; rr < 4; ++rr) {
      int qrow = qt * 64 + wave * 16 + quad * 4 + rr;
      Ob[(size_t)qrow * 768 + nt * 16 + l16] = (bf16)(acc[nt][rr] / l[rr]);
    }
  }
}

// ---------------------------------------------------------------------------
template <typename TY, typename TR, typename TO>
__global__ __launch_bounds__(256) void k_add_ln(const TY* __restrict__ Y,
                                                const TR* __restrict__ X,
                                                const float* __restrict__ g,
                                                const float* __restrict__ b,
                                                TO* __restrict__ out) {
  int wave = threadIdx.x >> 6, lane = threadIdx.x & 63;
  int row = blockIdx.x * 4 + wave;
  const TY* y = Y + (size_t)row * 768;
  const TR* x = X + (size_t)row * 768;
  float v[12];
  float s = 0.f, s2 = 0.f;
#pragma unroll
  for (int c = 0; c < 3; ++c) {
    int idx = c * 256 + lane * 4;
    float yv[4], xv[4];
    if constexpr (__is_same(TY, float)) {
      float4 t = *(const float4*)(y + idx);
      yv[0] = t.x; yv[1] = t.y; yv[2] = t.z; yv[3] = t.w;
    } else {
      bf16x4 t = *(const bf16x4*)(y + idx);
#pragma unroll
      for (int i = 0; i < 4; ++i) yv[i] = (float)t[i];
    }
    if constexpr (__is_same(TR, float)) {
      float4 t = *(const float4*)(x + idx);
      xv[0] = t.x; xv[1] = t.y; xv[2] = t.z; xv[3] = t.w;
    } else {
      bf16x4 t = *(const bf16x4*)(x + idx);
#pragma unroll
      for (int i = 0; i < 4; ++i) xv[i] = (float)t[i];
    }
#pragma unroll
    for (int i = 0; i < 4; ++i) {
      float t = yv[i] + xv[i];
      v[c * 4 + i] = t; s += t; s2 += t * t;
    }
  }
#pragma unroll
  for (int off = 32; off > 0; off >>= 1) { s += __shfl_xor(s, off); s2 += __shfl_xor(s2, off); }
  float mean = s * (1.f / 768.f);
  float var = fmaxf(s2 * (1.f / 768.f) - mean * mean, 0.f);
  float inv = rsqrtf(var + 1e-12f);
  TO* o = out + (size_t)row * 768;
#pragma unroll
  for (int c = 0; c < 3; ++c) {
    int idx = c * 256 + lane * 4;
    float4 gv = *(const float4*)(g + idx);
    float4 bv = *(const float4*)(b + idx);
    float r0 = (v[c * 4 + 0] - mean) * inv * gv.x + bv.x;
    float r1 = (v[c * 4 + 1] - mean) * inv * gv.y + bv.y;
    float r2 = (v[c * 4 + 2] - mean) * inv * gv.z + bv.z;
    float r3 = (v[c * 4 + 3] - mean) * inv * gv.w + bv.w;
    if constexpr (__is_same(TO, float)) {
      float4 ov = {r0, r1, r2, r3};
      *(float4*)(o + idx) = ov;
    } else {
      bf16x4 ov;
      ov[0] = (bf16)r0; ov[1] = (bf16)r1; ov[2] = (bf16)r2; ov[3] = (bf16)r3;
      *(bf16x4*)(o + idx) = ov;
    }
  }
}

// ---------------------------------------------------------------------------
extern "C" void kernel_launch(void* const* d_in, const int* in_sizes, int n_in,
                              void* d_out, int out_size, void* d_ws, size_t ws_size,
                              hipStream_t stream) {
  (void)in_sizes; (void)n_in; (void)out_size; (void)ws_size;
  const float* X     = (const float*)d_in[0];
  const float* tag   = (const float*)d_in[1];
  const float* sa_wq = (const float*)d_in[2];
  const float* sa_bq = (const float*)d_in[3];
  const float* sa_wk = (const float*)d_in[4];
  const float* sa_bk = (const float*)d_in[5];
  const float* sa_wv = (const float*)d_in[6];
  const float* sa_bv = (const float*)d_in[7];
  const float* sa_wo = (const float*)d_in[8];
  const float* sa_bo = (const float*)d_in[9];
  const float* sa_lg = (const float*)d_in[10];
  const float* sa_lb = (const float*)d_in[11];
  const float* ca_wq = (const float*)d_in[12];
  const float* ca_bq = (const float*)d_in[13];
  const float* ca_wk = (const float*)d_in[14];
  const float* ca_bk = (const float*)d_in[15];
  const float* ca_wv = (const float*)d_in[16];
  const float* ca_bv = (const float*)d_in[17];
  const float* ca_wo = (const float*)d_in[18];
  const float* ca_bo = (const float*)d_in[19];
  const float* ca_lg = (const float*)d_in[20];
  const float* ca_lb = (const float*)d_in[21];
  const float* ff_w1 = (const float*)d_in[22];
  const float* ff_b1 = (const float*)d_in[23];
  const float* ff_w2 = (const float*)d_in[24];
  const float* ff_b2 = (const float*)d_in[25];
  const float* ff_lg = (const float*)d_in[26];
  const float* ff_lb = (const float*)d_in[27];

  float* outf = (float*)d_out;
  bf16* outb = (bf16*)d_out;
  const size_t SLOT = (size_t)4096 * 768;

  // ---- ws: 34.60 MB ----
  bf16* BIG   = (bf16*)d_ws;                    // 4096x2304
  bf16* slotA = BIG + (size_t)4096 * 2304;      // residual chain
  bf16* Wall  = slotA + SLOT;                   // 3072x768
  bf16* W2    = Wall + (size_t)3072 * 768;      // 768x3072
  bf16* tagp  = W2;
  bf16* k2v2  = W2 + (size_t)128 * 768;
  float* bQKV = (float*)(W2 + (size_t)128 * 768 + (size_t)128 * 1536);
  float* bKV2 = bQKV + 2304;

  dim3 blk(256);

  k_concat3<<<dim3(9), blk, 0, stream>>>(sa_bq, sa_bk, sa_bv, bQKV, 768);
  k_concat3<<<dim3(6), blk, 0, stream>>>(ca_bk, ca_bv, nullptr, bKV2, 768);
  k_pad_tags<<<dim3(384), blk, 0, stream>>>(tag, tagp);

  // ---- self-attention ----
  k_transpose4<<<dim3(12, 12, 4), blk, 0, stream>>>(sa_wq, sa_wk, sa_wv, sa_wo, Wall);
  k_gemm<128, true, false><<<dim3(32, 18), blk, 0, stream>>>(X, Wall, bQKV, BIG,
                                                             4096, 2304, 768, 0);  // QKV
  k_attn_mfma<<<dim3(32, 24), blk, 0, stream>>>(BIG, 2304, BIG + 768, BIG + 1536, 2304,
                                                outb, 2048, 2048, (long long)2048 * 2304, 50);
  k_gemm<64, false, false><<<dim3(64, 6), blk, 0, stream>>>(outb, Wall + (size_t)2304 * 768,
                                                            sa_bo, slotA, 4096, 768, 768, 0);  // y1
  k_add_ln<bf16, float, bf16><<<dim3(1024), blk, 0, stream>>>(slotA, X, sa_lg, sa_lb, slotA);

  // ---- cross-attention ----
  k_transpose4<<<dim3(12, 12, 4), blk, 0, stream>>>(ca_wq, ca_wk, ca_wv, ca_wo, Wall);
  k_gemm<64, false, false><<<dim3(64, 6), blk, 0, stream>>>(slotA, Wall, ca_bq, BIG,
                                                            4096, 768, 768, 0);  // Q2
  k_gemm<64, false, false><<<dim3(2, 12), blk, 0, stream>>>(tagp, Wall + (size_t)768 * 768,
                                                            bKV2, k2v2, 128, 1536, 768, 0);  // K2V2
  k_attn_mfma<<<dim3(32, 24), blk, 0, stream>>>(BIG, 768, k2v2, k2v2 + 768, 1536,
                                                outb, 2048, 64, 0, -1);
  k_gemm<64, false, false><<<dim3(64, 6), blk, 0, stream>>>(outb, Wall + (size_t)2304 * 768,
                                                            ca_bo, BIG + SLOT, 4096, 768, 768, 0);  // y2
  k_add_ln<bf16, bf16, bf16><<<dim3(1024), blk, 0, stream>>>(BIG + SLOT, slotA, ca_lg, ca_lb, slotA);

  // ---- FFN: 2 M-chunks of 2048 rows via BIG ----
  k_transpose<<<dim3(48, 12), blk, 0, stream>>>(ff_w1, Wall, 768, 3072);  // ff1t [3072][768]
  k_transpose<<<dim3(12, 48), blk, 0, stream>>>(ff_w2, W2, 3072, 768);    // ff2t [768][3072]
  for (int mc = 0; mc < 2; ++mc) {
    const bf16* a2 = slotA + (size_t)mc * 2048 * 768;
    float* yo = outf + (size_t)mc * 2048 * 768;
    k_gemm<128, false, false><<<dim3(16, 24), blk, 0, stream>>>(a2, Wall, ff_b1, BIG,
                                                                2048, 3072, 768, 1);  // gelu inter
    k_gemm<64, false, true><<<dim3(32, 6), blk, 0, stream>>>(BIG, W2, ff_b2, yo,
                                                             2048, 768, 3072, 0);     // y3 fp32
    k_add_ln<float, bf16, float><<<dim3(512), blk, 0, stream>>>(yo, a2, ff_lg, ff_lb, yo);
  }
}

// Round 9
// 505.521 us; speedup vs baseline: 32.5348x; 1.0145x over previous
//
#include <hip/hip_runtime.h>
#include <cstdint>
#include <cstddef>

// B=2, S=2048, D=768, H=12, DH=64, T=64, R=50, FF=3072
// fp32 I/O, bf16 MFMA internals.
// R9: attention LDS diet. R8 accounting: LDS pipe ~84% busy (426 cyc/wave/chunk).
// (1) (q-half x key-half) wave split halves Ks+Vt reads; epilogue cross-wave
// O/l combine via LDS (aliased over dead Qs/Ks). (2) Vt staging packed b32
// (conflict-free). (3) Ps swizzle col'=(key+8*quad)&31 @ stride 40 (all 32
// banks per store instr, verified by enumeration). GEMMs unchanged from R8.

typedef __bf16 bf16;
typedef __bf16 bf16x8 __attribute__((ext_vector_type(8)));
typedef __bf16 bf16x4 __attribute__((ext_vector_type(4)));
typedef __bf16 bf16x2 __attribute__((ext_vector_type(2)));
typedef float  floatx4 __attribute__((ext_vector_type(4)));

__device__ __forceinline__ void glds16(const bf16* g, bf16* l) {
  __builtin_amdgcn_global_load_lds((const __attribute__((address_space(1))) void*)g,
                                   (__attribute__((address_space(3))) void*)l, 16, 0, 0);
}

// ---------------------------------------------------------------------------
__global__ __launch_bounds__(256) void k_concat3(const float* __restrict__ a,
                                                 const float* __restrict__ b,
                                                 const float* __restrict__ c,
                                                 float* __restrict__ o, int seg) {
  int i = blockIdx.x * 256 + threadIdx.x;
  int s = i / seg, j = i - s * seg;
  const float* p = s == 0 ? a : (s == 1 ? b : c);
  o[i] = p[j];
}

__global__ void k_pad_tags(const float* __restrict__ tag, bf16* __restrict__ out) {
  int i = blockIdx.x * 256 + threadIdx.x;
  if (i < 64 * 768) out[i] = (bf16)tag[i];
  else if (i < 128 * 768) out[i] = (bf16)0.f;
}

// ---------------------------------------------------------------------------
__global__ __launch_bounds__(256) void k_transpose(const float* __restrict__ W,
                                                   bf16* __restrict__ Wt,
                                                   int K, int N) {
  __shared__ bf16 tile[64][72];
  int n0 = blockIdx.x * 64, k0 = blockIdx.y * 64;
  int t = threadIdx.x;
  int r = t >> 2, cg = (t & 3) * 16;
  const float* src = W + (size_t)(k0 + r) * N + n0 + cg;
  float tmp[16];
  *(float4*)&tmp[0]  = *(const float4*)(src);
  *(float4*)&tmp[4]  = *(const float4*)(src + 4);
  *(float4*)&tmp[8]  = *(const float4*)(src + 8);
  *(float4*)&tmp[12] = *(const float4*)(src + 12);
#pragma unroll
  for (int i = 0; i < 16; ++i) tile[r][cg + i] = (bf16)tmp[i];
  __syncthreads();
  bf16* dst = Wt + (size_t)(n0 + r) * K + k0 + cg;
#pragma unroll
  for (int g = 0; g < 2; ++g) {
    bf16x8 pack;
#pragma unroll
    for (int i = 0; i < 8; ++i) pack[i] = tile[cg + g * 8 + i][r];
    *(bf16x8*)(dst + g * 8) = pack;
  }
}

__global__ __launch_bounds__(256) void k_transpose4(const float* __restrict__ W0,
                                                    const float* __restrict__ W1,
                                                    const float* __restrict__ W2w,
                                                    const float* __restrict__ W3,
                                                    bf16* __restrict__ Wt) {
  __shared__ bf16 tile[64][72];
  int z = blockIdx.z;
  const float* W = z == 0 ? W0 : (z == 1 ? W1 : (z == 2 ? W2w : W3));
  bf16* dstb = Wt + (size_t)z * 768 * 768;
  int n0 = blockIdx.x * 64, k0 = blockIdx.y * 64;
  int t = threadIdx.x;
  int r = t >> 2, cg = (t & 3) * 16;
  const float* src = W + (size_t)(k0 + r) * 768 + n0 + cg;
  float tmp[16];
  *(float4*)&tmp[0]  = *(const float4*)(src);
  *(float4*)&tmp[4]  = *(const float4*)(src + 4);
  *(float4*)&tmp[8]  = *(const float4*)(src + 8);
  *(float4*)&tmp[12] = *(const float4*)(src + 12);
#pragma unroll
  for (int i = 0; i < 16; ++i) tile[r][cg + i] = (bf16)tmp[i];
  __syncthreads();
  bf16* dst = dstb + (size_t)(n0 + r) * 768 + k0 + cg;
#pragma unroll
  for (int g = 0; g < 2; ++g) {
    bf16x8 pack;
#pragma unroll
    for (int i = 0; i < 8; ++i) pack[i] = tile[cg + g * 8 + i][r];
    *(bf16x8*)(dst + g * 8) = pack;
  }
}

// ---------------------------------------------------------------------------
// GEMM: C[M,N] = A[M,K] @ Bt[N,K]^T + bias. BMx128 tile, BK=32, glds staging.
template <int BM, bool AF32, bool CF32>
__global__ __launch_bounds__(256) void k_gemm(const void* __restrict__ Av,
                                              const bf16* __restrict__ Bt,
                                              const float* __restrict__ bias,
                                              void* __restrict__ Cv,
                                              int M, int N, int K, int act) {
  constexpr int MT = BM / 32;
  __shared__ bf16 As[BM * 32];
  __shared__ bf16 Bs[128 * 32];
  int tid = threadIdx.x;
  int lane = tid & 63, wave = tid >> 6;
  int l16 = lane & 15, quad = lane >> 4;
  int wm = wave & 1, wn = wave >> 1;
  int m0 = blockIdx.x * BM, n0 = blockIdx.y * 128;
  int arow = tid >> 2, acol = (tid & 3) * 8;
  int ldst = arow * 32 + acol;

  const bf16* Ab = (const bf16*)Av;
  const float* Af = (const float*)Av;
  const bf16* Ap = Ab + (size_t)(m0 + arow) * K + acol;
  const float* Apf = Af + (size_t)(m0 + arow) * K + acol;
  const bf16* Bp = Bt + (size_t)(n0 + arow) * K + acol;

  floatx4 acc[MT][4];
#pragma unroll
  for (int i = 0; i < MT; ++i)
#pragma unroll
    for (int j = 0; j < 4; ++j) acc[i][j] = floatx4{0.f, 0.f, 0.f, 0.f};

  float4 p0a, p0b, p1a, p1b;
  if constexpr (AF32) {
    p0a = *(const float4*)(Apf);
    p0b = *(const float4*)(Apf + 4);
    p1a = *(const float4*)(Apf + (size_t)64 * K);
    p1b = *(const float4*)(Apf + (size_t)64 * K + 4);
  }

  for (int k = 0; k < K; k += 32) {
    __syncthreads();
    glds16(Bp + k, &Bs[ldst]);
    glds16(Bp + (size_t)64 * K + k, &Bs[ldst + 2048]);
    if constexpr (AF32) {
      bf16x8 c0, c1;
      c0[0] = (bf16)p0a.x; c0[1] = (bf16)p0a.y; c0[2] = (bf16)p0a.z; c0[3] = (bf16)p0a.w;
      c0[4] = (bf16)p0b.x; c0[5] = (bf16)p0b.y; c0[6] = (bf16)p0b.z; c0[7] = (bf16)p0b.w;
      c1[0] = (bf16)p1a.x; c1[1] = (bf16)p1a.y; c1[2] = (bf16)p1a.z; c1[3] = (bf16)p1a.w;
      c1[4] = (bf16)p1b.x; c1[5] = (bf16)p1b.y; c1[6] = (bf16)p1b.z; c1[7] = (bf16)p1b.w;
      *(bf16x8*)&As[ldst] = c0;
      *(bf16x8*)&As[ldst + 2048] = c1;
    } else {
      glds16(Ap + k, &As[ldst]);
      if constexpr (BM == 128) glds16(Ap + (size_t)64 * K + k, &As[ldst + 2048]);
    }
    __syncthreads();
    if constexpr (AF32) {
      if (k + 32 < K) {
        p0a = *(const float4*)(Apf + k + 32);
        p0b = *(const float4*)(Apf + k + 36);
        p1a = *(const float4*)(Apf + (size_t)64 * K + k + 32);
        p1b = *(const float4*)(Apf + (size_t)64 * K + k + 36);
      }
    }
    bf16x8 a_frag[MT], b_frag[4];
#pragma unroll
    for (int mt = 0; mt < MT; ++mt)
      a_frag[mt] = *(const bf16x8*)&As[(wm * (BM / 2) + mt * 16 + l16) * 32 + quad * 8];
#pragma unroll
    for (int nt = 0; nt < 4; ++nt)
      b_frag[nt] = *(const bf16x8*)&Bs[(wn * 64 + nt * 16 + l16) * 32 + quad * 8];
#pragma unroll
    for (int mt = 0; mt < MT; ++mt)
#pragma unroll
      for (int nt = 0; nt < 4; ++nt)
        acc[mt][nt] = __builtin_amdgcn_mfma_f32_16x16x32_bf16(a_frag[mt], b_frag[nt], acc[mt][nt], 0, 0, 0);
  }

#pragma unroll
  for (int nt = 0; nt < 4; ++nt) {
    int col = n0 + wn * 64 + nt * 16 + l16;
    float bv = bias[col];
#pragma unroll
    for (int mt = 0; mt < MT; ++mt) {
#pragma unroll
      for (int r = 0; r < 4; ++r) {
        int row = m0 + wm * (BM / 2) + mt * 16 + quad * 4 + r;
        float v = acc[mt][nt][r] + bv;
        if (act) v = 0.5f * v * (1.f + erff(v * 0.70710678118654752f));
        if constexpr (CF32) ((float*)Cv)[(size_t)row * N + col] = v;
        else ((bf16*)Cv)[(size_t)row * N + col] = (bf16)v;
      }
    }
  }
}

// ---------------------------------------------------------------------------
// MFMA flash attention, max-free streaming softmax.
// Wave w: q-half qh=w&1 (32 rows), key-half kh=w>>1 (32 keys/chunk).
// Epilogue: kh=0 waves stage partial O (fp32) + l into LDS (aliased over
// dead Qs/Ks), kh=1 waves combine, divide, store.
__global__ __launch_bounds__(256) void k_attn_mfma(const bf16* __restrict__ Q, int ldq,
                                                   const bf16* __restrict__ Kp,
                                                   const bf16* __restrict__ Vp, int ldkv,
                                                   bf16* __restrict__ O,
                                                   int S, int Skv,
                                                   long long kv_bstride, int bandR) {
  const int NH = 12;
  int qt = blockIdx.x, bh = blockIdx.y;
  int bb = bh / NH, h = bh % NH;
  const bf16* Qb = Q + (size_t)bb * S * ldq + h * 64;
  const bf16* Kb = Kp + (size_t)bb * kv_bstride + h * 64;
  const bf16* Vb = Vp + (size_t)bb * kv_bstride + h * 64;
  bf16* Ob = O + (size_t)bb * S * 768 + h * 64;

  // layout: Qs[64][72] @0 (9216) | Ks[64][72] @9216 | Vt[64][72] @18432 |
  //         Ps 4 x [32][40] @27648 (10240)  => 37888 B
  // epilogue alias: Obuf fp32 [64][66] @0 (16896) | l0_arr[64] @16896
  __shared__ __align__(16) char smem[38912];
  bf16 (*Qs)[72] = (bf16(*)[72])(smem);
  bf16 (*Ks)[72] = (bf16(*)[72])(smem + 9216);
  bf16 (*Vt)[72] = (bf16(*)[72])(smem + 18432);
  float* Obuf = (float*)smem;
  float* l0_arr = (float*)(smem + 16896);

  int tid = threadIdx.x, wave = tid >> 6, lane = tid & 63;
  int quad = lane >> 4, l16 = lane & 15;
  int qh = wave & 1, kh = wave >> 1;
  bf16 (*Psw)[40] = (bf16(*)[40])(smem + 27648 + wave * 2560);

  int r = tid >> 2, cg = (tid & 3) * 16;
  {  // stage Q once
    const bf16* src = Qb + (size_t)(qt * 64 + r) * ldq + cg;
    *(bf16x8*)&Qs[r][cg] = *(const bf16x8*)src;
    *(bf16x8*)&Qs[r][cg + 8] = *(const bf16x8*)(src + 8);
  }
  __syncthreads();
  bf16x8 aq[2][2];  // [mt][ks] loop-invariant Q fragments
#pragma unroll
  for (int mt = 0; mt < 2; ++mt)
#pragma unroll
    for (int ks = 0; ks < 2; ++ks)
      aq[mt][ks] = *(const bf16x8*)&Qs[qh * 32 + mt * 16 + l16][ks * 32 + quad * 8];

  float l_part[2][4];
  floatx4 acc[2][4];
#pragma unroll
  for (int mt = 0; mt < 2; ++mt)
#pragma unroll
    for (int j = 0; j < 4; ++j) {
      l_part[mt][j] = 0.f;
      acc[mt][j] = floatx4{0.f, 0.f, 0.f, 0.f};
    }

  // V staging assignment: thread -> keys {vk0, vk0+1}, d = vd0..vd0+7
  int vk0 = 2 * (tid & 31);
  int vd0 = 8 * (tid >> 5);
  int vcol = (vk0 + 16 * (vd0 >> 4)) & 63;  // constant per thread (d-run stays in 16-block)

  const float C1 = 0.18033688f;   // log2(e)/8
  const float C2 = 1.44269504f;   // log2(e)
  int qi0 = qt * 64 + qh * 32 + quad * 4;

  for (int kc = 0; kc < Skv; kc += 64) {
    __syncthreads();
    {
      const bf16* ksrc = Kb + (size_t)(kc + r) * ldkv + cg;
      *(bf16x8*)&Ks[r][cg] = *(const bf16x8*)ksrc;
      *(bf16x8*)&Ks[r][cg + 8] = *(const bf16x8*)(ksrc + 8);
      const bf16* v0p = Vb + (size_t)(kc + vk0) * ldkv + vd0;
      bf16x8 v0 = *(const bf16x8*)v0p;
      bf16x8 v1 = *(const bf16x8*)(v0p + ldkv);
#pragma unroll
      for (int e = 0; e < 8; ++e) {
        bf16x2 p; p[0] = v0[e]; p[1] = v1[e];
        *(bf16x2*)&Vt[vd0 + e][vcol] = p;  // conflict-free b32 (verified)
      }
    }
    __syncthreads();

    // QK^T: this wave's 32 keys x its 32 q rows
    floatx4 s[2][2];
#pragma unroll
    for (int kt = 0; kt < 2; ++kt) {
      bf16x8 bk0 = *(const bf16x8*)&Ks[kh * 32 + kt * 16 + l16][quad * 8];
      bf16x8 bk1 = *(const bf16x8*)&Ks[kh * 32 + kt * 16 + l16][32 + quad * 8];
#pragma unroll
      for (int mt = 0; mt < 2; ++mt) {
        floatx4 c = {0.f, 0.f, 0.f, 0.f};
        c = __builtin_amdgcn_mfma_f32_16x16x32_bf16(aq[mt][0], bk0, c, 0, 0, 0);
        c = __builtin_amdgcn_mfma_f32_16x16x32_bf16(aq[mt][1], bk1, c, 0, 0, 0);
        s[mt][kt] = c;
      }
    }

    bool masked = (bandR >= 0) && (kc <= qt * 64 + 63 + bandR) &&
                  (kc + 63 >= qt * 64 - bandR);
    if (masked) {
#pragma unroll
      for (int kt = 0; kt < 2; ++kt) {
        int kj = kc + kh * 32 + kt * 16 + l16;
        int colp = (kt * 16 + l16 + 8 * quad) & 31;
#pragma unroll
        for (int mt = 0; mt < 2; ++mt)
#pragma unroll
          for (int rr = 0; rr < 4; ++rr) {
            int d = qi0 + mt * 16 + rr - kj; if (d < 0) d = -d;
            float e = exp2f(s[mt][kt][rr] * C1 + (d <= bandR ? C2 : 0.f));
            l_part[mt][rr] += e;
            Psw[mt * 16 + quad * 4 + rr][colp] = (bf16)e;
          }
      }
    } else {
#pragma unroll
      for (int kt = 0; kt < 2; ++kt) {
        int colp = (kt * 16 + l16 + 8 * quad) & 31;
#pragma unroll
        for (int mt = 0; mt < 2; ++mt)
#pragma unroll
          for (int rr = 0; rr < 4; ++rr) {
            float e = exp2f(s[mt][kt][rr] * C1);
            l_part[mt][rr] += e;
            Psw[mt * 16 + quad * 4 + rr][colp] = (bf16)e;
          }
      }
    }

    // PV over this wave's 32 keys
    bf16x8 ap[2];
#pragma unroll
    for (int mt = 0; mt < 2; ++mt)
      ap[mt] = *(const bf16x8*)&Psw[mt * 16 + l16][8 * ((quad + (l16 >> 2)) & 3)];
#pragma unroll
    for (int nt = 0; nt < 4; ++nt) {
      bf16x8 bv = *(const bf16x8*)&Vt[nt * 16 + l16][(kh * 32 + quad * 8 + 16 * nt) & 63];
#pragma unroll
      for (int mt = 0; mt < 2; ++mt)
        acc[mt][nt] = __builtin_amdgcn_mfma_f32_16x16x32_bf16(ap[mt], bv, acc[mt][nt], 0, 0, 0);
    }
  }

  // ---- epilogue: reduce l within quad, combine key-halves via LDS ----
  float lr[2][4];
#pragma unroll
  for (int mt = 0; mt < 2; ++mt)
#pragma unroll
    for (int rr = 0; rr < 4; ++rr) {
      float t = l_part[mt][rr];
      t += __shfl_xor(t, 1);
      t += __shfl_xor(t, 2);
      t += __shfl_xor(t, 4);
      t += __shfl_xor(t, 8);
      lr[mt][rr] = t;
    }
  __syncthreads();  // all LDS reads done before aliasing Obuf over Qs/Ks
  if (kh == 0) {
#pragma unroll
    for (int mt = 0; mt < 2; ++mt)
#pragma unroll
      for (int nt = 0; nt < 4; ++nt)
#pragma unroll
        for (int rr = 0; rr < 4; ++rr)
          Obuf[(qh * 32 + mt * 16 + quad * 4 + rr) * 66 + nt * 16 + l16] = acc[mt][nt][rr];
    if (l16 == 0) {
#pragma unroll
      for (int mt = 0; mt < 2; ++mt)
#pragma unroll
        for (int rr = 0; rr < 4; ++rr)
          l0_arr[qh * 32 + mt * 16 + quad * 4 + rr] = lr[mt][rr];
    }
  }
  __syncthreads();
  if (kh == 1) {
#pragma unroll
    for (int mt = 0; mt < 2; ++mt)
#pragma unroll
      for (int rr = 0; rr < 4; ++rr) {
        int ql = qh * 32 + mt * 16 + quad * 4 + rr;
        float lt = lr[mt][rr] + l0_arr[ql];
        int qrow = qt * 64 + ql;
#pragma unroll
        for (int nt = 0; nt < 4; ++nt) {
          float o = (acc[mt][nt][rr] + Obuf[ql * 66 + nt * 16 + l16]) / lt;
          Ob[(size_t)qrow * 768 + nt * 16 + l16] = (bf16)o;
        }
      }
  }
}

// ---------------------------------------------------------------------------
template <typename TY, typename TR, typename TO>
__global__ __launch_bounds__(256) void k_add_ln(const TY* __restrict__ Y,
                                                const TR* __restrict__ X,
                                                const float* __restrict__ g,
                                                const float* __restrict__ b,
                                                TO* __restrict__ out) {
  int wave = threadIdx.x >> 6, lane = threadIdx.x & 63;
  int row = blockIdx.x * 4 + wave;
  const TY* y = Y + (size_t)row * 768;
  const TR* x = X + (size_t)row * 768;
  float v[12];
  float s = 0.f, s2 = 0.f;
#pragma unroll
  for (int c = 0; c < 3; ++c) {
    int idx = c * 256 + lane * 4;
    float yv[4], xv[4];
    if constexpr (__is_same(TY, float)) {
      float4 t = *(const float4*)(y + idx);
      yv[0] = t.x; yv[1] = t.y; yv[2] = t.z; yv[3] = t.w;
    } else {
      bf16x4 t = *(const bf16x4*)(y + idx);
#pragma unroll
      for (int i = 0; i < 4; ++i) yv[i] = (float)t[i];
    }
    if constexpr (__is_same(TR, float)) {
      float4 t = *(const float4*)(x + idx);
      xv[0] = t.x; xv[1] = t.y; xv[2] = t.z; xv[3] = t.w;
    } else {
      bf16x4 t = *(const bf16x4*)(x + idx);
#pragma unroll
      for (int i = 0; i < 4; ++i) xv[i] = (float)t[i];
    }
#pragma unroll
    for (int i = 0; i < 4; ++i) {
      float t = yv[i] + xv[i];
      v[c * 4 + i] = t; s += t; s2 += t * t;
    }
  }
#pragma unroll
  for (int off = 32; off > 0; off >>= 1) { s += __shfl_xor(s, off); s2 += __shfl_xor(s2, off); }
  float mean = s * (1.f / 768.f);
  float var = fmaxf(s2 * (1.f / 768.f) - mean * mean, 0.f);
  float inv = rsqrtf(var + 1e-12f);
  TO* o = out + (size_t)row * 768;
#pragma unroll
  for (int c = 0; c < 3; ++c) {
    int idx = c * 256 + lane * 4;
    float4 gv = *(const float4*)(g + idx);
    float4 bv = *(const float4*)(b + idx);
    float r0 = (v[c * 4 + 0] - mean) * inv * gv.x + bv.x;
    float r1 = (v[c * 4 + 1] - mean) * inv * gv.y + bv.y;
    float r2 = (v[c * 4 + 2] - mean) * inv * gv.z + bv.z;
    float r3 = (v[c * 4 + 3] - mean) * inv * gv.w + bv.w;
    if constexpr (__is_same(TO, float)) {
      float4 ov = {r0, r1, r2, r3};
      *(float4*)(o + idx) = ov;
    } else {
      bf16x4 ov;
      ov[0] = (bf16)r0; ov[1] = (bf16)r1; ov[2] = (bf16)r2; ov[3] = (bf16)r3;
      *(bf16x4*)(o + idx) = ov;
    }
  }
}

// ---------------------------------------------------------------------------
extern "C" void kernel_launch(void* const* d_in, const int* in_sizes, int n_in,
                              void* d_out, int out_size, void* d_ws, size_t ws_size,
                              hipStream_t stream) {
  (void)in_sizes; (void)n_in; (void)out_size; (void)ws_size;
  const float* X     = (const float*)d_in[0];
  const float* tag   = (const float*)d_in[1];
  const float* sa_wq = (const float*)d_in[2];
  const float* sa_bq = (const float*)d_in[3];
  const float* sa_wk = (const float*)d_in[4];
  const float* sa_bk = (const float*)d_in[5];
  const float* sa_wv = (const float*)d_in[6];
  const float* sa_bv = (const float*)d_in[7];
  const float* sa_wo = (const float*)d_in[8];
  const float* sa_bo = (const float*)d_in[9];
  const float* sa_lg = (const float*)d_in[10];
  const float* sa_lb = (const float*)d_in[11];
  const float* ca_wq = (const float*)d_in[12];
  const float* ca_bq = (const float*)d_in[13];
  const float* ca_wk = (const float*)d_in[14];
  const float* ca_bk = (const float*)d_in[15];
  const float* ca_wv = (const float*)d_in[16];
  const float* ca_bv = (const float*)d_in[17];
  const float* ca_wo = (const float*)d_in[18];
  const float* ca_bo = (const float*)d_in[19];
  const float* ca_lg = (const float*)d_in[20];
  const float* ca_lb = (const float*)d_in[21];
  const float* ff_w1 = (const float*)d_in[22];
  const float* ff_b1 = (const float*)d_in[23];
  const float* ff_w2 = (const float*)d_in[24];
  const float* ff_b2 = (const float*)d_in[25];
  const float* ff_lg = (const float*)d_in[26];
  const float* ff_lb = (const float*)d_in[27];

  float* outf = (float*)d_out;
  bf16* outb = (bf16*)d_out;
  const size_t SLOT = (size_t)4096 * 768;

  // ---- ws: 34.60 MB ----
  bf16* BIG   = (bf16*)d_ws;                    // 4096x2304
  bf16* slotA = BIG + (size_t)4096 * 2304;      // residual chain
  bf16* Wall  = slotA + SLOT;                   // 3072x768
  bf16* W2    = Wall + (size_t)3072 * 768;      // 768x3072
  bf16* tagp  = W2;
  bf16* k2v2  = W2 + (size_t)128 * 768;
  float* bQKV = (float*)(W2 + (size_t)128 * 768 + (size_t)128 * 1536);
  float* bKV2 = bQKV + 2304;

  dim3 blk(256);

  k_concat3<<<dim3(9), blk, 0, stream>>>(sa_bq, sa_bk, sa_bv, bQKV, 768);
  k_concat3<<<dim3(6), blk, 0, stream>>>(ca_bk, ca_bv, nullptr, bKV2, 768);
  k_pad_tags<<<dim3(384), blk, 0, stream>>>(tag, tagp);

  // ---- self-attention ----
  k_transpose4<<<dim3(12, 12, 4), blk, 0, stream>>>(sa_wq, sa_wk, sa_wv, sa_wo, Wall);
  k_gemm<128, true, false><<<dim3(32, 18), blk, 0, stream>>>(X, Wall, bQKV, BIG,
                                                             4096, 2304, 768, 0);  // QKV
  k_attn_mfma<<<dim3(32, 24), blk, 0, stream>>>(BIG, 2304, BIG + 768, BIG + 1536, 2304,
                                                outb, 2048, 2048, (long long)2048 * 2304, 50);
  k_gemm<64, false, false><<<dim3(64, 6), blk, 0, stream>>>(outb, Wall + (size_t)2304 * 768,
                                                            sa_bo, slotA, 4096, 768, 768, 0);  // y1
  k_add_ln<bf16, float, bf16><<<dim3(1024), blk, 0, stream>>>(slotA, X, sa_lg, sa_lb, slotA);

  // ---- cross-attention ----
  k_transpose4<<<dim3(12, 12, 4), blk, 0, stream>>>(ca_wq, ca_wk, ca_wv, ca_wo, Wall);
  k_gemm<64, false, false><<<dim3(64, 6), blk, 0, stream>>>(slotA, Wall, ca_bq, BIG,
                                                            4096, 768, 768, 0);  // Q2
  k_gemm<64, false, false><<<dim3(2, 12), blk, 0, stream>>>(tagp, Wall + (size_t)768 * 768,
                                                            bKV2, k2v2, 128, 1536, 768, 0);  // K2V2
  k_attn_mfma<<<dim3(32, 24), blk, 0, stream>>>(BIG, 768, k2v2, k2v2 + 768, 1536,
                                                outb, 2048, 64, 0, -1);
  k_gemm<64, false, false><<<dim3(64, 6), blk, 0, stream>>>(outb, Wall + (size_t)2304 * 768,
                                                            ca_bo, BIG + SLOT, 4096, 768, 768, 0);  // y2
  k_add_ln<bf16, bf16, bf16><<<dim3(1024), blk, 0, stream>>>(BIG + SLOT, slotA, ca_lg, ca_lb, slotA);

  // ---- FFN: 2 M-chunks of 2048 rows via BIG ----
  k_transpose<<<dim3(48, 12), blk, 0, stream>>>(ff_w1, Wall, 768, 3072);  // ff1t [3072][768]
  k_transpose<<<dim3(12, 48), blk, 0, stream>>>(ff_w2, W2, 3072, 768);    // ff2t [768][3072]
  for (int mc = 0; mc < 2; ++mc) {
    const bf16* a2 = slotA + (size_t)mc * 2048 * 768;
    float* yo = outf + (size_t)mc * 2048 * 768;
    k_gemm<128, false, false><<<dim3(16, 24), blk, 0, stream>>>(a2, Wall, ff_b1, BIG,
                                                                2048, 3072, 768, 1);  // gelu inter
    k_gemm<64, false, true><<<dim3(32, 6), blk, 0, stream>>>(BIG, W2, ff_b2, yo,
                                                             2048, 768, 3072, 0);     // y3 fp32
    k_add_ln<float, bf16, float><<<dim3(512), blk, 0, stream>>>(yo, a2, ff_lg, ff_lb, yo);
  }
}

// Round 10
// 478.858 us; speedup vs baseline: 34.3464x; 1.0557x over previous
//
#include <hip/hip_runtime.h>
#include <cstdint>
#include <cstddef>

// B=2, S=2048, D=768, H=12, DH=64, T=64, R=50, FF=3072
// fp32 I/O, bf16 MFMA internals.
// R10: (1) GEMM KS=2 — two BK=32 sub-tiles per barrier pair (halves barrier
// drains; K=768: 24->12 iters). Contiguous BK=64 layout would be 2x the LDS
// b128 floor (16 lanes/bank-group), so k-split tiles keep BK=32 banking.
// (2) attention: Q pre-scaled by log2e/8 at staging -> hot loop is bare
// exp2f (R9 showed VALU-bound at 48.6% with exp/fma/cvt chain).

typedef __bf16 bf16;
typedef __bf16 bf16x8 __attribute__((ext_vector_type(8)));
typedef __bf16 bf16x4 __attribute__((ext_vector_type(4)));
typedef __bf16 bf16x2 __attribute__((ext_vector_type(2)));
typedef float  floatx4 __attribute__((ext_vector_type(4)));

__device__ __forceinline__ void glds16(const bf16* g, bf16* l) {
  __builtin_amdgcn_global_load_lds((const __attribute__((address_space(1))) void*)g,
                                   (__attribute__((address_space(3))) void*)l, 16, 0, 0);
}

// ---------------------------------------------------------------------------
__global__ __launch_bounds__(256) void k_concat3(const float* __restrict__ a,
                                                 const float* __restrict__ b,
                                                 const float* __restrict__ c,
                                                 float* __restrict__ o, int seg) {
  int i = blockIdx.x * 256 + threadIdx.x;
  int s = i / seg, j = i - s * seg;
  const float* p = s == 0 ? a : (s == 1 ? b : c);
  o[i] = p[j];
}

__global__ void k_pad_tags(const float* __restrict__ tag, bf16* __restrict__ out) {
  int i = blockIdx.x * 256 + threadIdx.x;
  if (i < 64 * 768) out[i] = (bf16)tag[i];
  else if (i < 128 * 768) out[i] = (bf16)0.f;
}

// ---------------------------------------------------------------------------
__global__ __launch_bounds__(256) void k_transpose(const float* __restrict__ W,
                                                   bf16* __restrict__ Wt,
                                                   int K, int N) {
  __shared__ bf16 tile[64][72];
  int n0 = blockIdx.x * 64, k0 = blockIdx.y * 64;
  int t = threadIdx.x;
  int r = t >> 2, cg = (t & 3) * 16;
  const float* src = W + (size_t)(k0 + r) * N + n0 + cg;
  float tmp[16];
  *(float4*)&tmp[0]  = *(const float4*)(src);
  *(float4*)&tmp[4]  = *(const float4*)(src + 4);
  *(float4*)&tmp[8]  = *(const float4*)(src + 8);
  *(float4*)&tmp[12] = *(const float4*)(src + 12);
#pragma unroll
  for (int i = 0; i < 16; ++i) tile[r][cg + i] = (bf16)tmp[i];
  __syncthreads();
  bf16* dst = Wt + (size_t)(n0 + r) * K + k0 + cg;
#pragma unroll
  for (int g = 0; g < 2; ++g) {
    bf16x8 pack;
#pragma unroll
    for (int i = 0; i < 8; ++i) pack[i] = tile[cg + g * 8 + i][r];
    *(bf16x8*)(dst + g * 8) = pack;
  }
}

__global__ __launch_bounds__(256) void k_transpose4(const float* __restrict__ W0,
                                                    const float* __restrict__ W1,
                                                    const float* __restrict__ W2w,
                                                    const float* __restrict__ W3,
                                                    bf16* __restrict__ Wt) {
  __shared__ bf16 tile[64][72];
  int z = blockIdx.z;
  const float* W = z == 0 ? W0 : (z == 1 ? W1 : (z == 2 ? W2w : W3));
  bf16* dstb = Wt + (size_t)z * 768 * 768;
  int n0 = blockIdx.x * 64, k0 = blockIdx.y * 64;
  int t = threadIdx.x;
  int r = t >> 2, cg = (t & 3) * 16;
  const float* src = W + (size_t)(k0 + r) * 768 + n0 + cg;
  float tmp[16];
  *(float4*)&tmp[0]  = *(const float4*)(src);
  *(float4*)&tmp[4]  = *(const float4*)(src + 4);
  *(float4*)&tmp[8]  = *(const float4*)(src + 8);
  *(float4*)&tmp[12] = *(const float4*)(src + 12);
#pragma unroll
  for (int i = 0; i < 16; ++i) tile[r][cg + i] = (bf16)tmp[i];
  __syncthreads();
  bf16* dst = dstb + (size_t)(n0 + r) * 768 + k0 + cg;
#pragma unroll
  for (int g = 0; g < 2; ++g) {
    bf16x8 pack;
#pragma unroll
    for (int i = 0; i < 8; ++i) pack[i] = tile[cg + g * 8 + i][r];
    *(bf16x8*)(dst + g * 8) = pack;
  }
}

// ---------------------------------------------------------------------------
// GEMM: C[M,N] = A[M,K] @ Bt[N,K]^T + bias. BMx128 tile, KS BK=32 sub-tiles
// per barrier pair (KS=2 halves barrier count). glds width-16 staging.
// AF32: fp32 A cvt in regs (KS=1 only). CF32: fp32 C out.
template <int BM, int KS, bool AF32, bool CF32>
__global__ __launch_bounds__(256) void k_gemm(const void* __restrict__ Av,
                                              const bf16* __restrict__ Bt,
                                              const float* __restrict__ bias,
                                              void* __restrict__ Cv,
                                              int M, int N, int K, int act) {
  constexpr int MT = BM / 32;
  __shared__ bf16 As[KS][BM * 32];
  __shared__ bf16 Bs[KS][128 * 32];
  int tid = threadIdx.x;
  int lane = tid & 63, wave = tid >> 6;
  int l16 = lane & 15, quad = lane >> 4;
  int wm = wave & 1, wn = wave >> 1;
  int m0 = blockIdx.x * BM, n0 = blockIdx.y * 128;
  int arow = tid >> 2, acol = (tid & 3) * 8;
  int ldst = arow * 32 + acol;  // = tid*8 elems (lane-contiguous glds pattern)

  const bf16* Ab = (const bf16*)Av;
  const float* Af = (const float*)Av;
  const bf16* Ap = Ab + (size_t)(m0 + arow) * K + acol;
  const float* Apf = Af + (size_t)(m0 + arow) * K + acol;
  const bf16* Bp = Bt + (size_t)(n0 + arow) * K + acol;

  floatx4 acc[MT][4];
#pragma unroll
  for (int i = 0; i < MT; ++i)
#pragma unroll
    for (int j = 0; j < 4; ++j) acc[i][j] = floatx4{0.f, 0.f, 0.f, 0.f};

  float4 p0a, p0b, p1a, p1b;
  if constexpr (AF32) {
    p0a = *(const float4*)(Apf);
    p0b = *(const float4*)(Apf + 4);
    p1a = *(const float4*)(Apf + (size_t)64 * K);
    p1b = *(const float4*)(Apf + (size_t)64 * K + 4);
  }

  for (int k = 0; k < K; k += 32 * KS) {
    __syncthreads();
#pragma unroll
    for (int ks = 0; ks < KS; ++ks) {
      glds16(Bp + k + ks * 32, &Bs[ks][ldst]);
      glds16(Bp + (size_t)64 * K + k + ks * 32, &Bs[ks][ldst + 2048]);
    }
    if constexpr (AF32) {
      bf16x8 c0, c1;
      c0[0] = (bf16)p0a.x; c0[1] = (bf16)p0a.y; c0[2] = (bf16)p0a.z; c0[3] = (bf16)p0a.w;
      c0[4] = (bf16)p0b.x; c0[5] = (bf16)p0b.y; c0[6] = (bf16)p0b.z; c0[7] = (bf16)p0b.w;
      c1[0] = (bf16)p1a.x; c1[1] = (bf16)p1a.y; c1[2] = (bf16)p1a.z; c1[3] = (bf16)p1a.w;
      c1[4] = (bf16)p1b.x; c1[5] = (bf16)p1b.y; c1[6] = (bf16)p1b.z; c1[7] = (bf16)p1b.w;
      *(bf16x8*)&As[0][ldst] = c0;
      *(bf16x8*)&As[0][ldst + 2048] = c1;
    } else {
#pragma unroll
      for (int ks = 0; ks < KS; ++ks) {
        glds16(Ap + k + ks * 32, &As[ks][ldst]);
        if constexpr (BM == 128) glds16(Ap + (size_t)64 * K + k + ks * 32, &As[ks][ldst + 2048]);
      }
    }
    __syncthreads();
    if constexpr (AF32) {
      if (k + 32 < K) {
        p0a = *(const float4*)(Apf + k + 32);
        p0b = *(const float4*)(Apf + k + 36);
        p1a = *(const float4*)(Apf + (size_t)64 * K + k + 32);
        p1b = *(const float4*)(Apf + (size_t)64 * K + k + 36);
      }
    }
#pragma unroll
    for (int ks = 0; ks < KS; ++ks) {
      bf16x8 a_frag[MT], b_frag[4];
#pragma unroll
      for (int mt = 0; mt < MT; ++mt)
        a_frag[mt] = *(const bf16x8*)&As[ks][(wm * (BM / 2) + mt * 16 + l16) * 32 + quad * 8];
#pragma unroll
      for (int nt = 0; nt < 4; ++nt)
        b_frag[nt] = *(const bf16x8*)&Bs[ks][(wn * 64 + nt * 16 + l16) * 32 + quad * 8];
#pragma unroll
      for (int mt = 0; mt < MT; ++mt)
#pragma unroll
        for (int nt = 0; nt < 4; ++nt)
          acc[mt][nt] = __builtin_amdgcn_mfma_f32_16x16x32_bf16(a_frag[mt], b_frag[nt], acc[mt][nt], 0, 0, 0);
    }
  }

#pragma unroll
  for (int nt = 0; nt < 4; ++nt) {
    int col = n0 + wn * 64 + nt * 16 + l16;
    float bv = bias[col];
#pragma unroll
    for (int mt = 0; mt < MT; ++mt) {
#pragma unroll
      for (int r = 0; r < 4; ++r) {
        int row = m0 + wm * (BM / 2) + mt * 16 + quad * 4 + r;
        float v = acc[mt][nt][r] + bv;
        if (act) v = 0.5f * v * (1.f + erff(v * 0.70710678118654752f));
        if constexpr (CF32) ((float*)Cv)[(size_t)row * N + col] = v;
        else ((bf16*)Cv)[(size_t)row * N + col] = (bf16)v;
      }
    }
  }
}

// ---------------------------------------------------------------------------
// MFMA flash attention, max-free streaming softmax.
// Q pre-scaled by log2e/8 at staging -> hot loop is bare exp2f.
// Wave w: q-half qh=w&1 (32 rows), key-half kh=w>>1 (32 keys/chunk).
__global__ __launch_bounds__(256) void k_attn_mfma(const bf16* __restrict__ Q, int ldq,
                                                   const bf16* __restrict__ Kp,
                                                   const bf16* __restrict__ Vp, int ldkv,
                                                   bf16* __restrict__ O,
                                                   int S, int Skv,
                                                   long long kv_bstride, int bandR) {
  const int NH = 12;
  int qt = blockIdx.x, bh = blockIdx.y;
  int bb = bh / NH, h = bh % NH;
  const bf16* Qb = Q + (size_t)bb * S * ldq + h * 64;
  const bf16* Kb = Kp + (size_t)bb * kv_bstride + h * 64;
  const bf16* Vb = Vp + (size_t)bb * kv_bstride + h * 64;
  bf16* Ob = O + (size_t)bb * S * 768 + h * 64;

  __shared__ __align__(16) char smem[38912];
  bf16 (*Qs)[72] = (bf16(*)[72])(smem);
  bf16 (*Ks)[72] = (bf16(*)[72])(smem + 9216);
  bf16 (*Vt)[72] = (bf16(*)[72])(smem + 18432);
  float* Obuf = (float*)smem;
  float* l0_arr = (float*)(smem + 16896);

  int tid = threadIdx.x, wave = tid >> 6, lane = tid & 63;
  int quad = lane >> 4, l16 = lane & 15;
  int qh = wave & 1, kh = wave >> 1;
  bf16 (*Psw)[40] = (bf16(*)[40])(smem + 27648 + wave * 2560);

  const float C1 = 0.18033688f;   // log2(e)/8
  const float C2 = 1.44269504f;   // log2(e)

  int r = tid >> 2, cg = (tid & 3) * 16;
  {  // stage Q once, pre-scaled by C1 (folds softmax scale into MFMA input)
    const bf16* src = Qb + (size_t)(qt * 64 + r) * ldq + cg;
    bf16x8 q0 = *(const bf16x8*)src;
    bf16x8 q1 = *(const bf16x8*)(src + 8);
#pragma unroll
    for (int e = 0; e < 8; ++e) { q0[e] = (bf16)((float)q0[e] * C1); q1[e] = (bf16)((float)q1[e] * C1); }
    *(bf16x8*)&Qs[r][cg] = q0;
    *(bf16x8*)&Qs[r][cg + 8] = q1;
  }
  __syncthreads();
  bf16x8 aq[2][2];
#pragma unroll
  for (int mt = 0; mt < 2; ++mt)
#pragma unroll
    for (int ks = 0; ks < 2; ++ks)
      aq[mt][ks] = *(const bf16x8*)&Qs[qh * 32 + mt * 16 + l16][ks * 32 + quad * 8];

  float l_part[2][4];
  floatx4 acc[2][4];
#pragma unroll
  for (int mt = 0; mt < 2; ++mt)
#pragma unroll
    for (int j = 0; j < 4; ++j) {
      l_part[mt][j] = 0.f;
      acc[mt][j] = floatx4{0.f, 0.f, 0.f, 0.f};
    }

  int vk0 = 2 * (tid & 31);
  int vd0 = 8 * (tid >> 5);
  int vcol = (vk0 + 16 * (vd0 >> 4)) & 63;

  int qi0 = qt * 64 + qh * 32 + quad * 4;

  for (int kc = 0; kc < Skv; kc += 64) {
    __syncthreads();
    {
      const bf16* ksrc = Kb + (size_t)(kc + r) * ldkv + cg;
      *(bf16x8*)&Ks[r][cg] = *(const bf16x8*)ksrc;
      *(bf16x8*)&Ks[r][cg + 8] = *(const bf16x8*)(ksrc + 8);
      const bf16* v0p = Vb + (size_t)(kc + vk0) * ldkv + vd0;
      bf16x8 v0 = *(const bf16x8*)v0p;
      bf16x8 v1 = *(const bf16x8*)(v0p + ldkv);
#pragma unroll
      for (int e = 0; e < 8; ++e) {
        bf16x2 p; p[0] = v0[e]; p[1] = v1[e];
        *(bf16x2*)&Vt[vd0 + e][vcol] = p;
      }
    }
    __syncthreads();

    floatx4 s[2][2];
#pragma unroll
    for (int kt = 0; kt < 2; ++kt) {
      bf16x8 bk0 = *(const bf16x8*)&Ks[kh * 32 + kt * 16 + l16][quad * 8];
      bf16x8 bk1 = *(const bf16x8*)&Ks[kh * 32 + kt * 16 + l16][32 + quad * 8];
#pragma unroll
      for (int mt = 0; mt < 2; ++mt) {
        floatx4 c = {0.f, 0.f, 0.f, 0.f};
        c = __builtin_amdgcn_mfma_f32_16x16x32_bf16(aq[mt][0], bk0, c, 0, 0, 0);
        c = __builtin_amdgcn_mfma_f32_16x16x32_bf16(aq[mt][1], bk1, c, 0, 0, 0);
        s[mt][kt] = c;
      }
    }

    bool masked = (bandR >= 0) && (kc <= qt * 64 + 63 + bandR) &&
                  (kc + 63 >= qt * 64 - bandR);
    if (masked) {
#pragma unroll
      for (int kt = 0; kt < 2; ++kt) {
        int kj = kc + kh * 32 + kt * 16 + l16;
        int colp = (kt * 16 + l16 + 8 * quad) & 31;
#pragma unroll
        for (int mt = 0; mt < 2; ++mt)
#pragma unroll
          for (int rr = 0; rr < 4; ++rr) {
            int d = qi0 + mt * 16 + rr - kj; if (d < 0) d = -d;
            float e = exp2f(s[mt][kt][rr] + (d <= bandR ? C2 : 0.f));
            l_part[mt][rr] += e;
            Psw[mt * 16 + quad * 4 + rr][colp] = (bf16)e;
          }
      }
    } else {
#pragma unroll
      for (int kt = 0; kt < 2; ++kt) {
        int colp = (kt * 16 + l16 + 8 * quad) & 31;
#pragma unroll
        for (int mt = 0; mt < 2; ++mt)
#pragma unroll
          for (int rr = 0; rr < 4; ++rr) {
            float e = exp2f(s[mt][kt][rr]);
            l_part[mt][rr] += e;
            Psw[mt * 16 + quad * 4 + rr][colp] = (bf16)e;
          }
      }
    }

    bf16x8 ap[2];
#pragma unroll
    for (int mt = 0; mt < 2; ++mt)
      ap[mt] = *(const bf16x8*)&Psw[mt * 16 + l16][8 * ((quad + (l16 >> 2)) & 3)];
#pragma unroll
    for (int nt = 0; nt < 4; ++nt) {
      bf16x8 bv = *(const bf16x8*)&Vt[nt * 16 + l16][(kh * 32 + quad * 8 + 16 * nt) & 63];
#pragma unroll
      for (int mt = 0; mt < 2; ++mt)
        acc[mt][nt] = __builtin_amdgcn_mfma_f32_16x16x32_bf16(ap[mt], bv, acc[mt][nt], 0, 0, 0);
    }
  }

  // ---- epilogue: reduce l within quad, combine key-halves via LDS ----
  float lr[2][4];
#pragma unroll
  for (int mt = 0; mt < 2; ++mt)
#pragma unroll
    for (int rr = 0; rr < 4; ++rr) {
      float t = l_part[mt][rr];
      t += __shfl_xor(t, 1);
      t += __shfl_xor(t, 2);
      t += __shfl_xor(t, 4);
      t += __shfl_xor(t, 8);
      lr[mt][rr] = t;
    }
  __syncthreads();
  if (kh == 0) {
#pragma unroll
    for (int mt = 0; mt < 2; ++mt)
#pragma unroll
      for (int nt = 0; nt < 4; ++nt)
#pragma unroll
        for (int rr = 0; rr < 4; ++rr)
          Obuf[(qh * 32 + mt * 16 + quad * 4 + rr) * 66 + nt * 16 + l16] = acc[mt][nt][rr];
    if (l16 == 0) {
#pragma unroll
      for (int mt = 0; mt < 2; ++mt)
#pragma unroll
        for (int rr = 0; rr < 4; ++rr)
          l0_arr[qh * 32 + mt * 16 + quad * 4 + rr] = lr[mt][rr];
    }
  }
  __syncthreads();
  if (kh == 1) {
#pragma unroll
    for (int mt = 0; mt < 2; ++mt)
#pragma unroll
      for (int rr = 0; rr < 4; ++rr) {
        int ql = qh * 32 + mt * 16 + quad * 4 + rr;
        float lt = lr[mt][rr] + l0_arr[ql];
        int qrow = qt * 64 + ql;
#pragma unroll
        for (int nt = 0; nt < 4; ++nt) {
          float o = (acc[mt][nt][rr] + Obuf[ql * 66 + nt * 16 + l16]) / lt;
          Ob[(size_t)qrow * 768 + nt * 16 + l16] = (bf16)o;
        }
      }
  }
}

// ---------------------------------------------------------------------------
template <typename TY, typename TR, typename TO>
__global__ __launch_bounds__(256) void k_add_ln(const TY* __restrict__ Y,
                                                const TR* __restrict__ X,
                                                const float* __restrict__ g,
                                                const float* __restrict__ b,
                                                TO* __restrict__ out) {
  int wave = threadIdx.x >> 6, lane = threadIdx.x & 63;
  int row = blockIdx.x * 4 + wave;
  const TY* y = Y + (size_t)row * 768;
  const TR* x = X + (size_t)row * 768;
  float v[12];
  float s = 0.f, s2 = 0.f;
#pragma unroll
  for (int c = 0; c < 3; ++c) {
    int idx = c * 256 + lane * 4;
    float yv[4], xv[4];
    if constexpr (__is_same(TY, float)) {
      float4 t = *(const float4*)(y + idx);
      yv[0] = t.x; yv[1] = t.y; yv[2] = t.z; yv[3] = t.w;
    } else {
      bf16x4 t = *(const bf16x4*)(y + idx);
#pragma unroll
      for (int i = 0; i < 4; ++i) yv[i] = (float)t[i];
    }
    if constexpr (__is_same(TR, float)) {
      float4 t = *(const float4*)(x + idx);
      xv[0] = t.x; xv[1] = t.y; xv[2] = t.z; xv[3] = t.w;
    } else {
      bf16x4 t = *(const bf16x4*)(x + idx);
#pragma unroll
      for (int i = 0; i < 4; ++i) xv[i] = (float)t[i];
    }
#pragma unroll
    for (int i = 0; i < 4; ++i) {
      float t = yv[i] + xv[i];
      v[c * 4 + i] = t; s += t; s2 += t * t;
    }
  }
#pragma unroll
  for (int off = 32; off > 0; off >>= 1) { s += __shfl_xor(s, off); s2 += __shfl_xor(s2, off); }
  float mean = s * (1.f / 768.f);
  float var = fmaxf(s2 * (1.f / 768.f) - mean * mean, 0.f);
  float inv = rsqrtf(var + 1e-12f);
  TO* o = out + (size_t)row * 768;
#pragma unroll
  for (int c = 0; c < 3; ++c) {
    int idx = c * 256 + lane * 4;
    float4 gv = *(const float4*)(g + idx);
    float4 bv = *(const float4*)(b + idx);
    float r0 = (v[c * 4 + 0] - mean) * inv * gv.x + bv.x;
    float r1 = (v[c * 4 + 1] - mean) * inv * gv.y + bv.y;
    float r2 = (v[c * 4 + 2] - mean) * inv * gv.z + bv.z;
    float r3 = (v[c * 4 + 3] - mean) * inv * gv.w + bv.w;
    if constexpr (__is_same(TO, float)) {
      float4 ov = {r0, r1, r2, r3};
      *(float4*)(o + idx) = ov;
    } else {
      bf16x4 ov;
      ov[0] = (bf16)r0; ov[1] = (bf16)r1; ov[2] = (bf16)r2; ov[3] = (bf16)r3;
      *(bf16x4*)(o + idx) = ov;
    }
  }
}

// ---------------------------------------------------------------------------
extern "C" void kernel_launch(void* const* d_in, const int* in_sizes, int n_in,
                              void* d_out, int out_size, void* d_ws, size_t ws_size,
                              hipStream_t stream) {
  (void)in_sizes; (void)n_in; (void)out_size; (void)ws_size;
  const float* X     = (const float*)d_in[0];
  const float* tag   = (const float*)d_in[1];
  const float* sa_wq = (const float*)d_in[2];
  const float* sa_bq = (const float*)d_in[3];
  const float* sa_wk = (const float*)d_in[4];
  const float* sa_bk = (const float*)d_in[5];
  const float* sa_wv = (const float*)d_in[6];
  const float* sa_bv = (const float*)d_in[7];
  const float* sa_wo = (const float*)d_in[8];
  const float* sa_bo = (const float*)d_in[9];
  const float* sa_lg = (const float*)d_in[10];
  const float* sa_lb = (const float*)d_in[11];
  const float* ca_wq = (const float*)d_in[12];
  const float* ca_bq = (const float*)d_in[13];
  const float* ca_wk = (const float*)d_in[14];
  const float* ca_bk = (const float*)d_in[15];
  const float* ca_wv = (const float*)d_in[16];
  const float* ca_bv = (const float*)d_in[17];
  const float* ca_wo = (const float*)d_in[18];
  const float* ca_bo = (const float*)d_in[19];
  const float* ca_lg = (const float*)d_in[20];
  const float* ca_lb = (const float*)d_in[21];
  const float* ff_w1 = (const float*)d_in[22];
  const float* ff_b1 = (const float*)d_in[23];
  const float* ff_w2 = (const float*)d_in[24];
  const float* ff_b2 = (const float*)d_in[25];
  const float* ff_lg = (const float*)d_in[26];
  const float* ff_lb = (const float*)d_in[27];

  float* outf = (float*)d_out;
  bf16* outb = (bf16*)d_out;
  const size_t SLOT = (size_t)4096 * 768;

  // ---- ws: 34.60 MB ----
  bf16* BIG   = (bf16*)d_ws;                    // 4096x2304
  bf16* slotA = BIG + (size_t)4096 * 2304;      // residual chain
  bf16* Wall  = slotA + SLOT;                   // 3072x768
  bf16* W2    = Wall + (size_t)3072 * 768;      // 768x3072
  bf16* tagp  = W2;
  bf16* k2v2  = W2 + (size_t)128 * 768;
  float* bQKV = (float*)(W2 + (size_t)128 * 768 + (size_t)128 * 1536);
  float* bKV2 = bQKV + 2304;

  dim3 blk(256);

  k_concat3<<<dim3(9), blk, 0, stream>>>(sa_bq, sa_bk, sa_bv, bQKV, 768);
  k_concat3<<<dim3(6), blk, 0, stream>>>(ca_bk, ca_bv, nullptr, bKV2, 768);
  k_pad_tags<<<dim3(384), blk, 0, stream>>>(tag, tagp);

  // ---- self-attention ----
  k_transpose4<<<dim3(12, 12, 4), blk, 0, stream>>>(sa_wq, sa_wk, sa_wv, sa_wo, Wall);
  k_gemm<128, 1, true, false><<<dim3(32, 18), blk, 0, stream>>>(X, Wall, bQKV, BIG,
                                                                4096, 2304, 768, 0);  // QKV
  k_attn_mfma<<<dim3(32, 24), blk, 0, stream>>>(BIG, 2304, BIG + 768, BIG + 1536, 2304,
                                                outb, 2048, 2048, (long long)2048 * 2304, 50);
  k_gemm<64, 2, false, false><<<dim3(64, 6), blk, 0, stream>>>(outb, Wall + (size_t)2304 * 768,
                                                               sa_bo, slotA, 4096, 768, 768, 0);  // y1
  k_add_ln<bf16, float, bf16><<<dim3(1024), blk, 0, stream>>>(slotA, X, sa_lg, sa_lb, slotA);

  // ---- cross-attention ----
  k_transpose4<<<dim3(12, 12, 4), blk, 0, stream>>>(ca_wq, ca_wk, ca_wv, ca_wo, Wall);
  k_gemm<64, 2, false, false><<<dim3(64, 6), blk, 0, stream>>>(slotA, Wall, ca_bq, BIG,
                                                               4096, 768, 768, 0);  // Q2
  k_gemm<64, 2, false, false><<<dim3(2, 12), blk, 0, stream>>>(tagp, Wall + (size_t)768 * 768,
                                                               bKV2, k2v2, 128, 1536, 768, 0);  // K2V2
  k_attn_mfma<<<dim3(32, 24), blk, 0, stream>>>(BIG, 768, k2v2, k2v2 + 768, 1536,
                                                outb, 2048, 64, 0, -1);
  k_gemm<64, 2, false, false><<<dim3(64, 6), blk, 0, stream>>>(outb, Wall + (size_t)2304 * 768,
                                                               ca_bo, BIG + SLOT, 4096, 768, 768, 0);  // y2
  k_add_ln<bf16, bf16, bf16><<<dim3(1024), blk, 0, stream>>>(BIG + SLOT, slotA, ca_lg, ca_lb, slotA);

  // ---- FFN: 2 M-chunks of 2048 rows via BIG ----
  k_transpose<<<dim3(48, 12), blk, 0, stream>>>(ff_w1, Wall, 768, 3072);  // ff1t [3072][768]
  k_transpose<<<dim3(12, 48), blk, 0, stream>>>(ff_w2, W2, 3072, 768);    // ff2t [768][3072]
  for (int mc = 0; mc < 2; ++mc) {
    const bf16* a2 = slotA + (size_t)mc * 2048 * 768;
    float* yo = outf + (size_t)mc * 2048 * 768;
    k_gemm<128, 2, false, false><<<dim3(16, 24), blk, 0, stream>>>(a2, Wall, ff_b1, BIG,
                                                                   2048, 3072, 768, 1);  // gelu inter
    k_gemm<64, 2, false, true><<<dim3(32, 6), blk, 0, stream>>>(BIG, W2, ff_b2, yo,
                                                                2048, 768, 3072, 0);     // y3 fp32
    k_add_ln<float, bf16, float><<<dim3(512), blk, 0, stream>>>(yo, a2, ff_lg, ff_lb, yo);
  }
}